// Round 9
// baseline (261.425 us; speedup 1.0000x reference)
//
#include <hip/hip_runtime.h>
#include <hip/hip_bf16.h>
#include <cstdint>
#include <math.h>

using bf16 = __hip_bfloat16;
typedef __attribute__((ext_vector_type(8))) short bf16x8;
typedef __attribute__((ext_vector_type(4))) float f32x4;

#define DEV __device__ __forceinline__

DEV float b2f(unsigned short u) { return __uint_as_float(((uint32_t)u) << 16); }
DEV float bfl(bf16 h) { return __bfloat162float(h); }
DEV short f2bs(float f) { bf16 h = __float2bfloat16(f); return *(short*)&h; }
// explicit bf16-pair pack: a in low 16 bits (lower address), b in high.
DEV uint32_t pk2(float a, float b) {
  return (uint32_t)(unsigned short)f2bs(a) |
         ((uint32_t)(unsigned short)f2bs(b) << 16);
}
DEV float ldv(const void* p, int isbf, int i) {
  return isbf ? bfl(((const bf16*)p)[i]) : ((const float*)p)[i];
}

// weight fragment: 8 contiguous elems at w[row*K + off] -> bf16x8
DEV bf16x8 load_wfrag(const void* w, int isbf, int row, int K, int off) {
  bf16x8 r;
  if (isbf) {
    r = *(const bf16x8*)((const short*)w + (size_t)row * K + off);
  } else {
    const float* f = (const float*)w + (size_t)row * K + off;
    float4 a = *(const float4*)f, b = *(const float4*)(f + 4);
    r[0] = f2bs(a.x); r[1] = f2bs(a.y); r[2] = f2bs(a.z); r[3] = f2bs(a.w);
    r[4] = f2bs(b.x); r[5] = f2bs(b.y); r[6] = f2bs(b.z); r[7] = f2bs(b.w);
  }
  return r;
}

// ---------------------------------------------------------------------------
// dtype sniffer — EXACT round-3 version (validated).
// ---------------------------------------------------------------------------
__global__ __launch_bounds__(256) void sniff_kernel(
    const unsigned short* __restrict__ xr, int* __restrict__ flag)
{
  int tid = threadIdx.x;
  int good = 0;
  for (int k = tid; k < 16384; k += 256) {
    unsigned short u = xr[2 * k];
    int e = (u >> 7) & 0xFF;
    good += (e >= 0x6A && e <= 0x86) ? 1 : 0;
  }
  __shared__ int r[256];
  r[tid] = good;
  __syncthreads();
  for (int off = 128; off; off >>= 1) {
    if (tid < off) r[tid] += r[tid + off];
    __syncthreads();
  }
  if (tid == 0) *flag = (r[0] > 9830) ? 1 : 0;
}

// ---------------------------------------------------------------------------
// transpose x [b][c(256)][n(4096)] (flag dtype) -> xT [b][n][c] bf16.
// EXACT round-3 version (validated).
// ---------------------------------------------------------------------------
__global__ __launch_bounds__(256) void transpose_x(
    const void* __restrict__ x, short* __restrict__ xT, const int* __restrict__ flag)
{
  const int isbf = *flag;
  __shared__ short lt[64 * 71];
  const int n0 = blockIdx.x * 64, c0 = blockIdx.y * 64, b = blockIdx.z;
  const int tid = threadIdx.x;
  for (int it = 0; it < 4; ++it) {
    int idx4 = it * 256 + tid;
    int ci = idx4 >> 4, n4 = (idx4 & 15) * 4;
    size_t go = ((size_t)(b * 256 + c0 + ci)) * 4096 + n0 + n4;
    if (isbf) {
      ushort4 v = *(const ushort4*)((const unsigned short*)x + go);
      lt[ci * 71 + n4 + 0] = v.x; lt[ci * 71 + n4 + 1] = v.y;
      lt[ci * 71 + n4 + 2] = v.z; lt[ci * 71 + n4 + 3] = v.w;
    } else {
      float4 v = *(const float4*)((const float*)x + go);
      lt[ci * 71 + n4 + 0] = f2bs(v.x); lt[ci * 71 + n4 + 1] = f2bs(v.y);
      lt[ci * 71 + n4 + 2] = f2bs(v.z); lt[ci * 71 + n4 + 3] = f2bs(v.w);
    }
  }
  __syncthreads();
  for (int it = 0; it < 4; ++it) {
    int idx4 = it * 256 + tid;
    int n = idx4 >> 4, c4 = (idx4 & 15) * 4;
    ushort4 v;
    v.x = (unsigned short)lt[(c4 + 0) * 71 + n];
    v.y = (unsigned short)lt[(c4 + 1) * 71 + n];
    v.z = (unsigned short)lt[(c4 + 2) * 71 + n];
    v.w = (unsigned short)lt[(c4 + 3) * 71 + n];
    *(ushort4*)(xT + ((size_t)(b * 4096 + n0 + n)) * 256 + c0 + c4) = v;
  }
}

// ---------------------------------------------------------------------------
// conv_tp: FUSED theta+phi 1x1 convs — round-12 version (VALIDATED round 6).
// Kept as the FALLBACK path when ws_size is too small for conv_tpg.
// ---------------------------------------------------------------------------
__global__ __launch_bounds__(256) void conv_tp_k(
    const short* __restrict__ xT,
    const void* __restrict__ w1, const void* __restrict__ b1, short* __restrict__ out1,
    const void* __restrict__ w2, const void* __restrict__ b2, short* __restrict__ out2,
    const int* __restrict__ flag)
{
  const int isbf = *flag;
  __shared__ short shA[64 * 264];
  __shared__ short shB[64 * 136];
  const int b = blockIdx.y, nbase = blockIdx.x * 64, tid = threadIdx.x;
  const int ln = tid & 15, q = (tid >> 4) & 3, wv = tid >> 6;
  for (int it = 0; it < 16; ++it) {
    int idx4 = it * 256 + tid;
    int n = idx4 >> 6, c4 = (idx4 & 63) * 4;
    *(ushort4*)&shA[n * 264 + c4] =
        *(const ushort4*)(xT + ((size_t)(b * 4096 + nbase + n)) * 256 + c4);
  }
  __syncthreads();
  f32x4 zero = {0.f, 0.f, 0.f, 0.f};
  f32x4 acc1[4][2], acc2[4][2];
  for (int nt = 0; nt < 4; ++nt)
    for (int ti = 0; ti < 2; ++ti) { acc1[nt][ti] = zero; acc2[nt][ti] = zero; }

  for (int kk = 0; kk < 8; ++kk) {
    int off = kk * 32 + q * 8;
    bf16x8 a[4];
    #pragma unroll
    for (int nt = 0; nt < 4; ++nt)
      a[nt] = *(const bf16x8*)&shA[(16 * nt + ln) * 264 + off];
    #pragma unroll
    for (int ti = 0; ti < 2; ++ti) {
      bf16x8 bw1 = load_wfrag(w1, isbf, 16 * (2 * wv + ti) + ln, 256, off);
      #pragma unroll
      for (int nt = 0; nt < 4; ++nt)
        acc1[nt][ti] = __builtin_amdgcn_mfma_f32_16x16x32_bf16(a[nt], bw1, acc1[nt][ti], 0, 0, 0);
    }
    #pragma unroll
    for (int ti = 0; ti < 2; ++ti) {
      bf16x8 bw2 = load_wfrag(w2, isbf, 16 * (2 * wv + ti) + ln, 256, off);
      #pragma unroll
      for (int nt = 0; nt < 4; ++nt)
        acc2[nt][ti] = __builtin_amdgcn_mfma_f32_16x16x32_bf16(a[nt], bw2, acc2[nt][ti], 0, 0, 0);
    }
  }
  {
    float bv[2];
    for (int ti = 0; ti < 2; ++ti) bv[ti] = ldv(b1, isbf, 16 * (2 * wv + ti) + ln);
    for (int nt = 0; nt < 4; ++nt)
      for (int ti = 0; ti < 2; ++ti)
        for (int r = 0; r < 4; ++r)
          shB[(16 * nt + q * 4 + r) * 136 + 16 * (2 * wv + ti) + ln] =
              f2bs(acc1[nt][ti][r] + bv[ti]);
    __syncthreads();
    for (int it = 0; it < 8; ++it) {
      int idx4 = it * 256 + tid;
      int n = idx4 >> 5, c4 = (idx4 & 31) * 4;
      *(ushort4*)(out1 + ((size_t)(b * 4096 + nbase + n)) * 128 + c4) =
          *(const ushort4*)&shB[n * 136 + c4];
    }
    __syncthreads();
  }
  {
    float bv[2];
    for (int ti = 0; ti < 2; ++ti) bv[ti] = ldv(b2, isbf, 16 * (2 * wv + ti) + ln);
    for (int nt = 0; nt < 4; ++nt)
      for (int ti = 0; ti < 2; ++ti)
        for (int r = 0; r < 4; ++r)
          shB[(16 * nt + q * 4 + r) * 136 + 16 * (2 * wv + ti) + ln] =
              f2bs(acc2[nt][ti][r] + bv[ti]);
    __syncthreads();
    for (int it = 0; it < 8; ++it) {
      int idx4 = it * 256 + tid;
      int n = idx4 >> 5, c4 = (idx4 & 31) * 4;
      *(ushort4*)(out2 + ((size_t)(b * 4096 + nbase + n)) * 128 + c4) =
          *(const ushort4*)&shB[n * 136 + c4];
    }
  }
}

// ---------------------------------------------------------------------------
// conv_tpg: FUSED theta+phi+g 1x1 convs — VALIDATED round 8.
// ---------------------------------------------------------------------------
__global__ __launch_bounds__(256) void conv_tpg_k(
    const short* __restrict__ xT,
    const void* __restrict__ w1, const void* __restrict__ b1, short* __restrict__ out1,
    const void* __restrict__ w2, const void* __restrict__ b2, short* __restrict__ out2,
    const void* __restrict__ w3, const void* __restrict__ b3, short* __restrict__ out3,
    const int* __restrict__ flag)
{
  const int isbf = *flag;
  __shared__ short shA[64 * 264];   // staging (persists through all epilogues)
  __shared__ short shB[8704];       // repack region (64*136 == 128*68)
  const int b = blockIdx.y, nbase = blockIdx.x * 64, tid = threadIdx.x;
  const int ln = tid & 15, q = (tid >> 4) & 3, wv = tid >> 6;
  for (int it = 0; it < 16; ++it) {
    int idx4 = it * 256 + tid;
    int n = idx4 >> 6, c4 = (idx4 & 63) * 4;
    *(ushort4*)&shA[n * 264 + c4] =
        *(const ushort4*)(xT + ((size_t)(b * 4096 + nbase + n)) * 256 + c4);
  }
  __syncthreads();
  f32x4 zero = {0.f, 0.f, 0.f, 0.f};
  f32x4 acc1[4][2], acc2[4][2], acc3[2][4];
  for (int nt = 0; nt < 4; ++nt)
    for (int ti = 0; ti < 2; ++ti) { acc1[nt][ti] = zero; acc2[nt][ti] = zero; }
  for (int ti = 0; ti < 2; ++ti)
    for (int nt = 0; nt < 4; ++nt) acc3[ti][nt] = zero;

  for (int kk = 0; kk < 8; ++kk) {
    int off = kk * 32 + q * 8;
    bf16x8 a[4];
    #pragma unroll
    for (int nt = 0; nt < 4; ++nt)
      a[nt] = *(const bf16x8*)&shA[(16 * nt + ln) * 264 + off];
    #pragma unroll
    for (int ti = 0; ti < 2; ++ti) {
      bf16x8 bw1 = load_wfrag(w1, isbf, 16 * (2 * wv + ti) + ln, 256, off);
      #pragma unroll
      for (int nt = 0; nt < 4; ++nt)
        acc1[nt][ti] = __builtin_amdgcn_mfma_f32_16x16x32_bf16(a[nt], bw1, acc1[nt][ti], 0, 0, 0);
    }
    #pragma unroll
    for (int ti = 0; ti < 2; ++ti) {
      bf16x8 bw2 = load_wfrag(w2, isbf, 16 * (2 * wv + ti) + ln, 256, off);
      #pragma unroll
      for (int nt = 0; nt < 4; ++nt)
        acc2[nt][ti] = __builtin_amdgcn_mfma_f32_16x16x32_bf16(a[nt], bw2, acc2[nt][ti], 0, 0, 0);
    }
    #pragma unroll
    for (int ti = 0; ti < 2; ++ti) {
      bf16x8 aw3 = load_wfrag(w3, isbf, 16 * (2 * wv + ti) + ln, 256, off);
      #pragma unroll
      for (int nt = 0; nt < 4; ++nt)
        acc3[ti][nt] = __builtin_amdgcn_mfma_f32_16x16x32_bf16(aw3, a[nt], acc3[ti][nt], 0, 0, 0);
    }
  }
  // epilogue 1 (theta -> out1 [b][n][128])
  {
    float bv[2];
    for (int ti = 0; ti < 2; ++ti) bv[ti] = ldv(b1, isbf, 16 * (2 * wv + ti) + ln);
    for (int nt = 0; nt < 4; ++nt)
      for (int ti = 0; ti < 2; ++ti)
        for (int r = 0; r < 4; ++r)
          shB[(16 * nt + q * 4 + r) * 136 + 16 * (2 * wv + ti) + ln] =
              f2bs(acc1[nt][ti][r] + bv[ti]);
    __syncthreads();
    for (int it = 0; it < 8; ++it) {
      int idx4 = it * 256 + tid;
      int n = idx4 >> 5, c4 = (idx4 & 31) * 4;
      *(ushort4*)(out1 + ((size_t)(b * 4096 + nbase + n)) * 128 + c4) =
          *(const ushort4*)&shB[n * 136 + c4];
    }
    __syncthreads();
  }
  // epilogue 2 (phi_c -> out2 [b][n][128])
  {
    float bv[2];
    for (int ti = 0; ti < 2; ++ti) bv[ti] = ldv(b2, isbf, 16 * (2 * wv + ti) + ln);
    for (int nt = 0; nt < 4; ++nt)
      for (int ti = 0; ti < 2; ++ti)
        for (int r = 0; r < 4; ++r)
          shB[(16 * nt + q * 4 + r) * 136 + 16 * (2 * wv + ti) + ln] =
              f2bs(acc2[nt][ti][r] + bv[ti]);
    __syncthreads();
    for (int it = 0; it < 8; ++it) {
      int idx4 = it * 256 + tid;
      int n = idx4 >> 5, c4 = (idx4 & 31) * 4;
      *(ushort4*)(out2 + ((size_t)(b * 4096 + nbase + n)) * 128 + c4) =
          *(const ushort4*)&shB[n * 136 + c4];
    }
    __syncthreads();
  }
  // epilogue 3 (g_c -> out3 [b][128][n], validated conv_n CO=128 pattern)
  {
    for (int ti = 0; ti < 2; ++ti)
      for (int r = 0; r < 4; ++r) {
        int co = 16 * (2 * wv + ti) + q * 4 + r;
        float bb = ldv(b3, isbf, co);
        for (int nt = 0; nt < 4; ++nt)
          shB[co * 68 + 16 * nt + ln] = f2bs(acc3[ti][nt][r] + bb);
      }
    __syncthreads();
    for (int it = 0; it < 8; ++it) {
      int idx4 = it * 256 + tid;
      int co = idx4 >> 4, n4 = (idx4 & 15) * 4;
      *(ushort4*)(out3 + ((size_t)(b * 128 + co)) * 4096 + nbase + n4) =
          *(const ushort4*)&shB[co * 68 + n4];
    }
  }
}

// ---------------------------------------------------------------------------
// conv_n: out[b][CO][n] — EXACT round-3 version (validated, fallback path).
// ---------------------------------------------------------------------------
template<int CO, int K>
__global__ __launch_bounds__(256) void conv_n_k(
    const short* __restrict__ inp, const void* __restrict__ w,
    const void* __restrict__ bias, short* __restrict__ out,
    const int* __restrict__ flag)
{
  const int isbf = *flag;
  constexpr int XS = 64 * (K + 8);
  constexpr int OS = CO * 68;
  __shared__ short sh[(XS > OS ? XS : OS)];
  const int b = blockIdx.y, nbase = blockIdx.x * 64, tid = threadIdx.x;
  const int ln = tid & 15, q = (tid >> 4) & 3, wv = tid >> 6;
  constexpr int TPW = CO / 64;
  constexpr int KS = (K == 256) ? 6 : 5;
  for (int it = 0; it < 64 * K / 1024; ++it) {
    int idx4 = it * 256 + tid;
    int n = idx4 >> KS, c4 = (idx4 & ((K / 4) - 1)) * 4;
    *(ushort4*)&sh[n * (K + 8) + c4] =
        *(const ushort4*)(inp + ((size_t)(b * 4096 + nbase + n)) * K + c4);
  }
  __syncthreads();
  f32x4 zero = {0.f, 0.f, 0.f, 0.f};
  f32x4 acc[TPW][4];
  for (int ti = 0; ti < TPW; ++ti) for (int nt = 0; nt < 4; ++nt) acc[ti][nt] = zero;

  for (int kk = 0; kk < K / 32; ++kk) {
    int off = kk * 32 + q * 8;
    bf16x8 bx[4];
    #pragma unroll
    for (int nt = 0; nt < 4; ++nt)
      bx[nt] = *(const bf16x8*)&sh[(16 * nt + ln) * (K + 8) + off];
    #pragma unroll
    for (int ti = 0; ti < TPW; ++ti) {
      bf16x8 aw = load_wfrag(w, isbf, 16 * (TPW * wv + ti) + ln, K, off);
      #pragma unroll
      for (int nt = 0; nt < 4; ++nt)
        acc[ti][nt] = __builtin_amdgcn_mfma_f32_16x16x32_bf16(aw, bx[nt], acc[ti][nt], 0, 0, 0);
    }
  }
  __syncthreads();
  for (int ti = 0; ti < TPW; ++ti)
    for (int r = 0; r < 4; ++r) {
      int co = 16 * (TPW * wv + ti) + q * 4 + r;
      float bb = ldv(bias, isbf, co);
      for (int nt = 0; nt < 4; ++nt)
        sh[co * 68 + 16 * nt + ln] = f2bs(acc[ti][nt][r] + bb);
    }
  __syncthreads();
  for (int it = 0; it < 64 * CO / 1024; ++it) {
    int idx4 = it * 256 + tid;
    int co = idx4 >> 4, n4 = (idx4 & 15) * 4;
    *(ushort4*)(out + ((size_t)(b * CO + co)) * 4096 + nbase + n4) =
        *(const ushort4*)&sh[co * 68 + n4];
  }
}

// ---------------------------------------------------------------------------
// pools — EXACT round-3 versions (validated) + fused variant (validated r8).
// ---------------------------------------------------------------------------
__global__ __launch_bounds__(256) void pool_phi_kernel(
    const short* __restrict__ pc, short* __restrict__ phi)
{
  int idx = blockIdx.x * 256 + threadIdx.x;  // b*1024*128
  int ci = idx & 127, m = (idx >> 7) & 1023, b = idx >> 17;
  int mh = m >> 5, mw = m & 31;
  const short* p = pc + ((size_t)(b * 4096 + (mh * 2) * 64 + mw * 2)) * 128 + ci;
  float v = fmaxf(fmaxf(b2f(p[0]), b2f(p[128])),
                  fmaxf(b2f(p[64 * 128]), b2f(p[65 * 128])));
  phi[idx] = f2bs(v);
}

__global__ __launch_bounds__(256) void pool_g_kernel(
    const short* __restrict__ gc, short* __restrict__ g)
{
  int idx = blockIdx.x * 256 + threadIdx.x;  // (b*128+ci)*1024 + m
  int m = idx & 1023, bc = idx >> 10;
  int mh = m >> 5, mw = m & 31;
  const short* p = gc + (size_t)bc * 4096 + mh * 128 + mw * 2;
  float v = fmaxf(fmaxf(b2f(p[0]), b2f(p[1])), fmaxf(b2f(p[64]), b2f(p[65])));
  g[idx] = f2bs(v);
}

__global__ __launch_bounds__(256) void pool_both_kernel(
    const short* __restrict__ pc, short* __restrict__ phi,
    const short* __restrict__ gc, short* __restrict__ g)
{
  int gidx = blockIdx.x * 256 + threadIdx.x;
  if (gidx < 1048576) {
    int idx = gidx;
    int ci = idx & 127, m = (idx >> 7) & 1023, b = idx >> 17;
    int mh = m >> 5, mw = m & 31;
    const short* p = pc + ((size_t)(b * 4096 + (mh * 2) * 64 + mw * 2)) * 128 + ci;
    float v = fmaxf(fmaxf(b2f(p[0]), b2f(p[128])),
                    fmaxf(b2f(p[64 * 128]), b2f(p[65 * 128])));
    phi[idx] = f2bs(v);
  } else {
    int idx = gidx - 1048576;
    int m = idx & 1023, bc = idx >> 10;
    int mh = m >> 5, mw = m & 31;
    const short* p = gc + (size_t)bc * 4096 + mh * 128 + mw * 2;
    float v = fmaxf(fmaxf(b2f(p[0]), b2f(p[1])), fmaxf(b2f(p[64]), b2f(p[65])));
    g[idx] = f2bs(v);
  }
}

// ---------------------------------------------------------------------------
// MFMA flash attention — ROUND-15: validated round-6 structure, with the gl
// LDS staging replaced by direct-global bg fragment loads (T14 issue-early/
// consume-late). Rationale: round-6 counters show ~66 LDS ops/wave/iter with
// the LDS pipe ~44% of runtime; bg fragments are identical across all 4
// waves (L1-broadcast) and g is L2-resident (256 KB/batch); loads issued
// BEFORE QK^T so ~250cy of MFMA/softmax hides L1/L2 latency (round-7's
// failure was removing BOTH stagings with no hiding). bg addresses are the
// exact ones field-verified in round-7's passing kernel. ph staging, Pl,
// epilogue: byte-identical to validated.  LDS 45056 -> 26624.
// ---------------------------------------------------------------------------
__global__ __launch_bounds__(256) void attn_kernel(
    const short* __restrict__ theta, const short* __restrict__ phi,
    const short* __restrict__ g, short* __restrict__ y)
{
  __shared__ short ph[64 * 136];
  __shared__ short Pl[64 * 72];
  const int b = blockIdx.y, nbase = blockIdx.x * 64, tid = threadIdx.x;
  const int ln = tid & 15, q = (tid >> 4) & 3, wv = tid >> 6;

  const int pm  = tid >> 5;          // ph row base (0..7), rows pm+8*it
  const int pc4 = (tid & 31) * 4;    // ph col (shorts)
  const short* phb = phi + (size_t)b * 1024 * 128;
  const short* gb  = g   + (size_t)b * 128 * 1024;

  // prefetch phi tile 0 into registers (validated pattern)
  ushort4 pf_p[8];
  #pragma unroll
  for (int it = 0; it < 8; ++it)
    pf_p[it] = *(const ushort4*)(phb + ((size_t)(pm + 8 * it)) * 128 + pc4);

  // Q fragments: loop-invariant, straight from global (validated pattern)
  bf16x8 a[4];
  #pragma unroll
  for (int kk = 0; kk < 4; ++kk)
    a[kk] = *(const bf16x8*)(theta +
        ((size_t)(b * 4096 + nbase + 16 * wv + ln)) * 128 + kk * 32 + q * 8);

  f32x4 zero = {0.f, 0.f, 0.f, 0.f};
  f32x4 yacc[8], lacc = zero;
  #pragma unroll
  for (int t = 0; t < 8; ++t) yacc[t] = zero;
  bf16x8 ones;
  #pragma unroll
  for (int j = 0; j < 8; ++j) ones[j] = 0x3F80;

  for (int mc = 0; mc < 16; ++mc) {
    // commit prefetched phi tile to LDS
    #pragma unroll
    for (int it = 0; it < 8; ++it)
      *(ushort4*)&ph[(pm + 8 * it) * 136 + pc4] = pf_p[it];
    __syncthreads();

    // issue next phi tile's global loads (hidden under compute below)
    if (mc < 15) {
      const int nmc = mc + 1;
      #pragma unroll
      for (int it = 0; it < 8; ++it)
        pf_p[it] = *(const ushort4*)(phb +
            ((size_t)(nmc * 64 + pm + 8 * it)) * 128 + pc4);
    }

    // issue THIS iter's g B-fragments (global; identical addrs across the
    // 4 waves -> L1 broadcast; consumed after QK^T+softmax hides latency).
    // Addresses = gl-staging composition, field-verified in round-7:
    //   g[(b*128 + 16t+ln)*1024 + mc*64 + kk*32 + q*8]
    bf16x8 bgr[16];
    #pragma unroll
    for (int t = 0; t < 8; ++t)
      #pragma unroll
      for (int kk = 0; kk < 2; ++kk)
        bgr[2 * t + kk] = *(const bf16x8*)(gb +
            ((size_t)(16 * t + ln)) * 1024 + mc * 64 + kk * 32 + q * 8);

    // QK^T -> exp -> P (intra-wave LDS transpose), l-acc  (validated)
    #pragma unroll
    for (int t = 0; t < 4; ++t) {
      f32x4 s = zero;
      #pragma unroll
      for (int kk = 0; kk < 4; ++kk) {
        bf16x8 bp = *(const bf16x8*)&ph[(16 * t + ln) * 136 + kk * 32 + q * 8];
        s = __builtin_amdgcn_mfma_f32_16x16x32_bf16(a[kk], bp, s, 0, 0, 0);
      }
      #pragma unroll
      for (int r = 0; r < 4; ++r)
        Pl[(16 * wv + q * 4 + r) * 72 + 16 * t + ln] =
            f2bs(__expf(fminf(s[r], 80.f)));
    }
    bf16x8 ap[2];
    #pragma unroll
    for (int kk = 0; kk < 2; ++kk)
      ap[kk] = *(const bf16x8*)&Pl[(16 * wv + ln) * 72 + kk * 32 + q * 8];
    #pragma unroll
    for (int kk = 0; kk < 2; ++kk)
      lacc = __builtin_amdgcn_mfma_f32_16x16x32_bf16(ap[kk], ones, lacc, 0, 0, 0);
    // PV: consume the prefetched bg fragments
    #pragma unroll
    for (int t = 0; t < 8; ++t) {
      #pragma unroll
      for (int kk = 0; kk < 2; ++kk)
        yacc[t] = __builtin_amdgcn_mfma_f32_16x16x32_bf16(ap[kk], bgr[2 * t + kk], yacc[t], 0, 0, 0);
    }
    __syncthreads();
  }

  float li[4];
  #pragma unroll
  for (int r = 0; r < 4; ++r) li[r] = 1.0f / lacc[r];
  for (int t = 0; t < 8; ++t)
    for (int r = 0; r < 4; ++r)
      ph[(16 * wv + q * 4 + r) * 136 + 16 * t + ln] = f2bs(yacc[t][r] * li[r]);
  __syncthreads();
  for (int it = 0; it < 8; ++it) {
    int idx4 = it * 256 + tid;
    int n = idx4 >> 5, c4 = (idx4 & 31) * 4;
    *(ushort4*)(y + ((size_t)(b * 4096 + nbase + n)) * 128 + c4) =
        *(const ushort4*)&ph[n * 136 + c4];
  }
}

// ---------------------------------------------------------------------------
// conv_W + BN partial-stat atomics — EXACT round-4 version (validated).
// ---------------------------------------------------------------------------
__global__ __launch_bounds__(256, 4) void convW_k(
    const short* __restrict__ yb, const void* __restrict__ w,
    const void* __restrict__ bias, short* __restrict__ Wy,
    float* __restrict__ stats, const int* __restrict__ flag)
{
  const int isbf = *flag;
  __shared__ short sh[256 * 72];
  const int b = blockIdx.y, nbase = blockIdx.x * 64, tid = threadIdx.x;
  const int ln = tid & 15, q = (tid >> 4) & 3, wv = tid >> 6;

  for (int it = 0; it < 4; ++it) {
    int idx8 = it * 256 + tid;
    int n = idx8 >> 4, c8 = (idx8 & 15) * 8;
    *(uint4*)&sh[n * 136 + c8] =
        *(const uint4*)(yb + ((size_t)(b * 4096 + nbase + n)) * 128 + c8);
  }
  __syncthreads();
  f32x4 zero = {0.f, 0.f, 0.f, 0.f};
  f32x4 acc[4][4];
  for (int ti = 0; ti < 4; ++ti)
    for (int nt = 0; nt < 4; ++nt) acc[ti][nt] = zero;

  for (int kk = 0; kk < 4; ++kk) {
    int off = kk * 32 + q * 8;
    bf16x8 bx[4];
    #pragma unroll
    for (int nt = 0; nt < 4; ++nt)
      bx[nt] = *(const bf16x8*)&sh[(16 * nt + ln) * 136 + off];
    #pragma unroll
    for (int ti = 0; ti < 4; ++ti) {
      bf16x8 aw = load_wfrag(w, isbf, 16 * (4 * wv + ti) + ln, 128, off);
      #pragma unroll
      for (int nt = 0; nt < 4; ++nt)
        acc[ti][nt] = __builtin_amdgcn_mfma_f32_16x16x32_bf16(aw, bx[nt], acc[ti][nt], 0, 0, 0);
    }
  }
  __syncthreads();
  #pragma unroll
  for (int ti = 0; ti < 4; ++ti)
    #pragma unroll
    for (int r = 0; r < 4; ++r) {
      int co = 16 * (4 * wv + ti) + 4 * q + r;
      float bb = ldv(bias, isbf, co);
      #pragma unroll
      for (int nt = 0; nt < 4; ++nt)
        sh[co * 72 + 16 * nt + ln] = f2bs(acc[ti][nt][r] + bb);
    }
  __syncthreads();
  {
    int co = tid;
    float s = 0.f, s2 = 0.f;
    for (int i = 0; i < 64; ++i) {
      float v = b2f((unsigned short)sh[co * 72 + i]);
      s += v; s2 += v * v;
    }
    atomicAdd(&stats[co], s);
    atomicAdd(&stats[256 + co], s2);
  }
  for (int it = 0; it < 8; ++it) {
    int idx8 = it * 256 + tid;
    int co = idx8 >> 3, n8 = (idx8 & 7) * 8;
    *(uint4*)(Wy + ((size_t)(b * 256 + co)) * 4096 + nbase + n8) =
        *(const uint4*)&sh[co * 72 + n8];
  }
}

// ---------------------------------------------------------------------------
// BN apply + residual, x4 — EXACT round-4/6 version (validated).
// ---------------------------------------------------------------------------
__global__ __launch_bounds__(256) void bn_apply4(
    const short* __restrict__ Wy, const void* __restrict__ x,
    const float* __restrict__ stats, const void* __restrict__ gamma,
    const void* __restrict__ beta, void* __restrict__ out,
    const int* __restrict__ flag)
{
  const int isbf = *flag;
  int t = blockIdx.x * 256 + threadIdx.x;
  int idx4 = t * 4;
  int c = (idx4 >> 12) & 255;
  float s = stats[c], s2 = stats[256 + c];
  float mean = s * (1.0f / 32768.0f);
  float var = fmaxf(s2 * (1.0f / 32768.0f) - mean * mean, 0.f);
  float scale = rsqrtf(var + 1e-5f) * ldv(gamma, isbf, c);
  float shift = ldv(beta, isbf, c) - mean * scale;
  ushort4 wy = *(const ushort4*)(Wy + idx4);
  float xv[4];
  if (isbf) {
    ushort4 xu = *(const ushort4*)((const unsigned short*)x + idx4);
    xv[0] = b2f(xu.x); xv[1] = b2f(xu.y); xv[2] = b2f(xu.z); xv[3] = b2f(xu.w);
  } else {
    float4 xf = *(const float4*)((const float*)x + idx4);
    xv[0] = xf.x; xv[1] = xf.y; xv[2] = xf.z; xv[3] = xf.w;
  }
  float v0 = b2f(wy.x) * scale + shift + xv[0];
  float v1 = b2f(wy.y) * scale + shift + xv[1];
  float v2 = b2f(wy.z) * scale + shift + xv[2];
  float v3 = b2f(wy.w) * scale + shift + xv[3];
  if (isbf) {
    uint2 o; o.x = pk2(v0, v1); o.y = pk2(v2, v3);
    *(uint2*)((unsigned short*)out + idx4) = o;
  } else {
    float4 o = make_float4(v0, v1, v2, v3);
    *(float4*)((float*)out + idx4) = o;
  }
}

// ---------------------------------------------------------------------------
extern "C" void kernel_launch(void* const* d_in, const int* in_sizes, int n_in,
                              void* d_out, int out_size, void* d_ws, size_t ws_size,
                              hipStream_t stream) {
  const void* x       = d_in[0];
  const void* theta_w = d_in[1];
  const void* theta_b = d_in[2];
  const void* phi_w   = d_in[3];
  const void* phi_b   = d_in[4];
  const void* g_w     = d_in[5];
  const void* g_b     = d_in[6];
  const void* W_w     = d_in[7];
  const void* W_b     = d_in[8];
  const void* gamma   = d_in[9];
  const void* beta    = d_in[10];

  char* wsb = (char*)d_ws;
  // round-3 layout + optional g_c extension:
  //   [0, 16.78M)      xT -> ybuf
  //   [16.78M, 25.17M) theta -> W_y first half
  //   [25.17M, 33.55M) scratch (phi_c; g_c too on fallback path) -> W_y 2nd
  //   [33.55M, 35.65M) phi   [b][m][ci]
  //   [35.65M, 37.75M) gg    [b][ci][m]
  //   [37.75M, +2048)  stats (512 f32), flag
  //   [37.753M, 46.14M) g_c (fused path only, if ws_size permits)
  short* xT      = (short*)(wsb + 0);
  short* ybuf    = (short*)(wsb + 0);
  short* theta   = (short*)(wsb + 16777216);
  short* W_y     = (short*)(wsb + 16777216);
  short* scratch = (short*)(wsb + 25165824);
  short* phi     = (short*)(wsb + 33554432);
  short* gg      = (short*)(wsb + 35651584);
  float* stats   = (float*)(wsb + 37748736);
  int*   flag    = (int*)  (wsb + 37750784);
  short* g_c     = (short*)(wsb + 37752832);
  const bool fused = ws_size >= (size_t)37752832 + 8388608;

  dim3 blk(256);
  dim3 cgrid(64, 8);
  dim3 tgrid(64, 4, 8);

  hipMemsetAsync(stats, 0, 2048, stream);
  sniff_kernel<<<1, blk, 0, stream>>>((const unsigned short*)x, flag);
  transpose_x<<<tgrid, blk, 0, stream>>>(x, xT, flag);
  if (fused) {
    conv_tpg_k<<<cgrid, blk, 0, stream>>>(xT, theta_w, theta_b, theta,
                                          phi_w, phi_b, scratch,
                                          g_w, g_b, g_c, flag);
    pool_both_kernel<<<8192, blk, 0, stream>>>(scratch, phi, g_c, gg);
  } else {
    conv_tp_k<<<cgrid, blk, 0, stream>>>(xT, theta_w, theta_b, theta,
                                         phi_w, phi_b, scratch, flag);
    pool_phi_kernel<<<4096, blk, 0, stream>>>(scratch, phi);
    conv_n_k<128, 256><<<cgrid, blk, 0, stream>>>(xT, g_w, g_b, scratch, flag);
    pool_g_kernel<<<4096, blk, 0, stream>>>(scratch, gg);
  }
  attn_kernel<<<cgrid, blk, 0, stream>>>(theta, phi, gg, ybuf);
  convW_k<<<cgrid, blk, 0, stream>>>(ybuf, W_w, W_b, W_y, stats, flag);
  bn_apply4<<<8192, blk, 0, stream>>>(W_y, x, stats, gamma, beta, d_out, flag);
}

// Round 11
// 221.389 us; speedup vs baseline: 1.1808x; 1.1808x over previous
//
#include <hip/hip_runtime.h>
#include <hip/hip_bf16.h>
#include <cstdint>
#include <math.h>

using bf16 = __hip_bfloat16;
typedef __attribute__((ext_vector_type(8))) short bf16x8;
typedef __attribute__((ext_vector_type(4))) float f32x4;

#define DEV __device__ __forceinline__

DEV float b2f(unsigned short u) { return __uint_as_float(((uint32_t)u) << 16); }
DEV float bfl(bf16 h) { return __bfloat162float(h); }
DEV short f2bs(float f) { bf16 h = __float2bfloat16(f); return *(short*)&h; }
// explicit bf16-pair pack: a in low 16 bits (lower address), b in high.
DEV uint32_t pk2(float a, float b) {
  return (uint32_t)(unsigned short)f2bs(a) |
         ((uint32_t)(unsigned short)f2bs(b) << 16);
}
DEV float ldv(const void* p, int isbf, int i) {
  return isbf ? bfl(((const bf16*)p)[i]) : ((const float*)p)[i];
}

// weight fragment: 8 contiguous elems at w[row*K + off] -> bf16x8
DEV bf16x8 load_wfrag(const void* w, int isbf, int row, int K, int off) {
  bf16x8 r;
  if (isbf) {
    r = *(const bf16x8*)((const short*)w + (size_t)row * K + off);
  } else {
    const float* f = (const float*)w + (size_t)row * K + off;
    float4 a = *(const float4*)f, b = *(const float4*)(f + 4);
    r[0] = f2bs(a.x); r[1] = f2bs(a.y); r[2] = f2bs(a.z); r[3] = f2bs(a.w);
    r[4] = f2bs(b.x); r[5] = f2bs(b.y); r[6] = f2bs(b.z); r[7] = f2bs(b.w);
  }
  return r;
}

// ---------------------------------------------------------------------------
// dtype sniffer — EXACT round-3 version (validated).
// ---------------------------------------------------------------------------
__global__ __launch_bounds__(256) void sniff_kernel(
    const unsigned short* __restrict__ xr, int* __restrict__ flag)
{
  int tid = threadIdx.x;
  int good = 0;
  for (int k = tid; k < 16384; k += 256) {
    unsigned short u = xr[2 * k];
    int e = (u >> 7) & 0xFF;
    good += (e >= 0x6A && e <= 0x86) ? 1 : 0;
  }
  __shared__ int r[256];
  r[tid] = good;
  __syncthreads();
  for (int off = 128; off; off >>= 1) {
    if (tid < off) r[tid] += r[tid + off];
    __syncthreads();
  }
  if (tid == 0) *flag = (r[0] > 9830) ? 1 : 0;
}

// ---------------------------------------------------------------------------
// transpose x [b][c(256)][n(4096)] (flag dtype) -> xT [b][n][c] bf16.
// EXACT round-3 version (validated).
// ---------------------------------------------------------------------------
__global__ __launch_bounds__(256) void transpose_x(
    const void* __restrict__ x, short* __restrict__ xT, const int* __restrict__ flag)
{
  const int isbf = *flag;
  __shared__ short lt[64 * 71];
  const int n0 = blockIdx.x * 64, c0 = blockIdx.y * 64, b = blockIdx.z;
  const int tid = threadIdx.x;
  for (int it = 0; it < 4; ++it) {
    int idx4 = it * 256 + tid;
    int ci = idx4 >> 4, n4 = (idx4 & 15) * 4;
    size_t go = ((size_t)(b * 256 + c0 + ci)) * 4096 + n0 + n4;
    if (isbf) {
      ushort4 v = *(const ushort4*)((const unsigned short*)x + go);
      lt[ci * 71 + n4 + 0] = v.x; lt[ci * 71 + n4 + 1] = v.y;
      lt[ci * 71 + n4 + 2] = v.z; lt[ci * 71 + n4 + 3] = v.w;
    } else {
      float4 v = *(const float4*)((const float*)x + go);
      lt[ci * 71 + n4 + 0] = f2bs(v.x); lt[ci * 71 + n4 + 1] = f2bs(v.y);
      lt[ci * 71 + n4 + 2] = f2bs(v.z); lt[ci * 71 + n4 + 3] = f2bs(v.w);
    }
  }
  __syncthreads();
  for (int it = 0; it < 4; ++it) {
    int idx4 = it * 256 + tid;
    int n = idx4 >> 4, c4 = (idx4 & 15) * 4;
    ushort4 v;
    v.x = (unsigned short)lt[(c4 + 0) * 71 + n];
    v.y = (unsigned short)lt[(c4 + 1) * 71 + n];
    v.z = (unsigned short)lt[(c4 + 2) * 71 + n];
    v.w = (unsigned short)lt[(c4 + 3) * 71 + n];
    *(ushort4*)(xT + ((size_t)(b * 4096 + n0 + n)) * 256 + c0 + c4) = v;
  }
}

// ---------------------------------------------------------------------------
// conv_tp: FUSED theta+phi 1x1 convs — round-12 version (VALIDATED round 6).
// Kept as the FALLBACK path when ws_size is too small for conv_tpg.
// ---------------------------------------------------------------------------
__global__ __launch_bounds__(256) void conv_tp_k(
    const short* __restrict__ xT,
    const void* __restrict__ w1, const void* __restrict__ b1, short* __restrict__ out1,
    const void* __restrict__ w2, const void* __restrict__ b2, short* __restrict__ out2,
    const int* __restrict__ flag)
{
  const int isbf = *flag;
  __shared__ short shA[64 * 264];
  __shared__ short shB[64 * 136];
  const int b = blockIdx.y, nbase = blockIdx.x * 64, tid = threadIdx.x;
  const int ln = tid & 15, q = (tid >> 4) & 3, wv = tid >> 6;
  for (int it = 0; it < 16; ++it) {
    int idx4 = it * 256 + tid;
    int n = idx4 >> 6, c4 = (idx4 & 63) * 4;
    *(ushort4*)&shA[n * 264 + c4] =
        *(const ushort4*)(xT + ((size_t)(b * 4096 + nbase + n)) * 256 + c4);
  }
  __syncthreads();
  f32x4 zero = {0.f, 0.f, 0.f, 0.f};
  f32x4 acc1[4][2], acc2[4][2];
  for (int nt = 0; nt < 4; ++nt)
    for (int ti = 0; ti < 2; ++ti) { acc1[nt][ti] = zero; acc2[nt][ti] = zero; }

  for (int kk = 0; kk < 8; ++kk) {
    int off = kk * 32 + q * 8;
    bf16x8 a[4];
    #pragma unroll
    for (int nt = 0; nt < 4; ++nt)
      a[nt] = *(const bf16x8*)&shA[(16 * nt + ln) * 264 + off];
    #pragma unroll
    for (int ti = 0; ti < 2; ++ti) {
      bf16x8 bw1 = load_wfrag(w1, isbf, 16 * (2 * wv + ti) + ln, 256, off);
      #pragma unroll
      for (int nt = 0; nt < 4; ++nt)
        acc1[nt][ti] = __builtin_amdgcn_mfma_f32_16x16x32_bf16(a[nt], bw1, acc1[nt][ti], 0, 0, 0);
    }
    #pragma unroll
    for (int ti = 0; ti < 2; ++ti) {
      bf16x8 bw2 = load_wfrag(w2, isbf, 16 * (2 * wv + ti) + ln, 256, off);
      #pragma unroll
      for (int nt = 0; nt < 4; ++nt)
        acc2[nt][ti] = __builtin_amdgcn_mfma_f32_16x16x32_bf16(a[nt], bw2, acc2[nt][ti], 0, 0, 0);
    }
  }
  {
    float bv[2];
    for (int ti = 0; ti < 2; ++ti) bv[ti] = ldv(b1, isbf, 16 * (2 * wv + ti) + ln);
    for (int nt = 0; nt < 4; ++nt)
      for (int ti = 0; ti < 2; ++ti)
        for (int r = 0; r < 4; ++r)
          shB[(16 * nt + q * 4 + r) * 136 + 16 * (2 * wv + ti) + ln] =
              f2bs(acc1[nt][ti][r] + bv[ti]);
    __syncthreads();
    for (int it = 0; it < 8; ++it) {
      int idx4 = it * 256 + tid;
      int n = idx4 >> 5, c4 = (idx4 & 31) * 4;
      *(ushort4*)(out1 + ((size_t)(b * 4096 + nbase + n)) * 128 + c4) =
          *(const ushort4*)&shB[n * 136 + c4];
    }
    __syncthreads();
  }
  {
    float bv[2];
    for (int ti = 0; ti < 2; ++ti) bv[ti] = ldv(b2, isbf, 16 * (2 * wv + ti) + ln);
    for (int nt = 0; nt < 4; ++nt)
      for (int ti = 0; ti < 2; ++ti)
        for (int r = 0; r < 4; ++r)
          shB[(16 * nt + q * 4 + r) * 136 + 16 * (2 * wv + ti) + ln] =
              f2bs(acc2[nt][ti][r] + bv[ti]);
    __syncthreads();
    for (int it = 0; it < 8; ++it) {
      int idx4 = it * 256 + tid;
      int n = idx4 >> 5, c4 = (idx4 & 31) * 4;
      *(ushort4*)(out2 + ((size_t)(b * 4096 + nbase + n)) * 128 + c4) =
          *(const ushort4*)&shB[n * 136 + c4];
    }
  }
}

// ---------------------------------------------------------------------------
// conv_tpg: FUSED theta+phi+g 1x1 convs — VALIDATED round 8.
// ---------------------------------------------------------------------------
__global__ __launch_bounds__(256) void conv_tpg_k(
    const short* __restrict__ xT,
    const void* __restrict__ w1, const void* __restrict__ b1, short* __restrict__ out1,
    const void* __restrict__ w2, const void* __restrict__ b2, short* __restrict__ out2,
    const void* __restrict__ w3, const void* __restrict__ b3, short* __restrict__ out3,
    const int* __restrict__ flag)
{
  const int isbf = *flag;
  __shared__ short shA[64 * 264];   // staging (persists through all epilogues)
  __shared__ short shB[8704];       // repack region (64*136 == 128*68)
  const int b = blockIdx.y, nbase = blockIdx.x * 64, tid = threadIdx.x;
  const int ln = tid & 15, q = (tid >> 4) & 3, wv = tid >> 6;
  for (int it = 0; it < 16; ++it) {
    int idx4 = it * 256 + tid;
    int n = idx4 >> 6, c4 = (idx4 & 63) * 4;
    *(ushort4*)&shA[n * 264 + c4] =
        *(const ushort4*)(xT + ((size_t)(b * 4096 + nbase + n)) * 256 + c4);
  }
  __syncthreads();
  f32x4 zero = {0.f, 0.f, 0.f, 0.f};
  f32x4 acc1[4][2], acc2[4][2], acc3[2][4];
  for (int nt = 0; nt < 4; ++nt)
    for (int ti = 0; ti < 2; ++ti) { acc1[nt][ti] = zero; acc2[nt][ti] = zero; }
  for (int ti = 0; ti < 2; ++ti)
    for (int nt = 0; nt < 4; ++nt) acc3[ti][nt] = zero;

  for (int kk = 0; kk < 8; ++kk) {
    int off = kk * 32 + q * 8;
    bf16x8 a[4];
    #pragma unroll
    for (int nt = 0; nt < 4; ++nt)
      a[nt] = *(const bf16x8*)&shA[(16 * nt + ln) * 264 + off];
    #pragma unroll
    for (int ti = 0; ti < 2; ++ti) {
      bf16x8 bw1 = load_wfrag(w1, isbf, 16 * (2 * wv + ti) + ln, 256, off);
      #pragma unroll
      for (int nt = 0; nt < 4; ++nt)
        acc1[nt][ti] = __builtin_amdgcn_mfma_f32_16x16x32_bf16(a[nt], bw1, acc1[nt][ti], 0, 0, 0);
    }
    #pragma unroll
    for (int ti = 0; ti < 2; ++ti) {
      bf16x8 bw2 = load_wfrag(w2, isbf, 16 * (2 * wv + ti) + ln, 256, off);
      #pragma unroll
      for (int nt = 0; nt < 4; ++nt)
        acc2[nt][ti] = __builtin_amdgcn_mfma_f32_16x16x32_bf16(a[nt], bw2, acc2[nt][ti], 0, 0, 0);
    }
    #pragma unroll
    for (int ti = 0; ti < 2; ++ti) {
      bf16x8 aw3 = load_wfrag(w3, isbf, 16 * (2 * wv + ti) + ln, 256, off);
      #pragma unroll
      for (int nt = 0; nt < 4; ++nt)
        acc3[ti][nt] = __builtin_amdgcn_mfma_f32_16x16x32_bf16(aw3, a[nt], acc3[ti][nt], 0, 0, 0);
    }
  }
  // epilogue 1 (theta -> out1 [b][n][128])
  {
    float bv[2];
    for (int ti = 0; ti < 2; ++ti) bv[ti] = ldv(b1, isbf, 16 * (2 * wv + ti) + ln);
    for (int nt = 0; nt < 4; ++nt)
      for (int ti = 0; ti < 2; ++ti)
        for (int r = 0; r < 4; ++r)
          shB[(16 * nt + q * 4 + r) * 136 + 16 * (2 * wv + ti) + ln] =
              f2bs(acc1[nt][ti][r] + bv[ti]);
    __syncthreads();
    for (int it = 0; it < 8; ++it) {
      int idx4 = it * 256 + tid;
      int n = idx4 >> 5, c4 = (idx4 & 31) * 4;
      *(ushort4*)(out1 + ((size_t)(b * 4096 + nbase + n)) * 128 + c4) =
          *(const ushort4*)&shB[n * 136 + c4];
    }
    __syncthreads();
  }
  // epilogue 2 (phi_c -> out2 [b][n][128])
  {
    float bv[2];
    for (int ti = 0; ti < 2; ++ti) bv[ti] = ldv(b2, isbf, 16 * (2 * wv + ti) + ln);
    for (int nt = 0; nt < 4; ++nt)
      for (int ti = 0; ti < 2; ++ti)
        for (int r = 0; r < 4; ++r)
          shB[(16 * nt + q * 4 + r) * 136 + 16 * (2 * wv + ti) + ln] =
              f2bs(acc2[nt][ti][r] + bv[ti]);
    __syncthreads();
    for (int it = 0; it < 8; ++it) {
      int idx4 = it * 256 + tid;
      int n = idx4 >> 5, c4 = (idx4 & 31) * 4;
      *(ushort4*)(out2 + ((size_t)(b * 4096 + nbase + n)) * 128 + c4) =
          *(const ushort4*)&shB[n * 136 + c4];
    }
    __syncthreads();
  }
  // epilogue 3 (g_c -> out3 [b][128][n], validated conv_n CO=128 pattern)
  {
    for (int ti = 0; ti < 2; ++ti)
      for (int r = 0; r < 4; ++r) {
        int co = 16 * (2 * wv + ti) + q * 4 + r;
        float bb = ldv(b3, isbf, co);
        for (int nt = 0; nt < 4; ++nt)
          shB[co * 68 + 16 * nt + ln] = f2bs(acc3[ti][nt][r] + bb);
      }
    __syncthreads();
    for (int it = 0; it < 8; ++it) {
      int idx4 = it * 256 + tid;
      int co = idx4 >> 4, n4 = (idx4 & 15) * 4;
      *(ushort4*)(out3 + ((size_t)(b * 128 + co)) * 4096 + nbase + n4) =
          *(const ushort4*)&shB[co * 68 + n4];
    }
  }
}

// ---------------------------------------------------------------------------
// conv_n: out[b][CO][n] — EXACT round-3 version (validated, fallback path).
// ---------------------------------------------------------------------------
template<int CO, int K>
__global__ __launch_bounds__(256) void conv_n_k(
    const short* __restrict__ inp, const void* __restrict__ w,
    const void* __restrict__ bias, short* __restrict__ out,
    const int* __restrict__ flag)
{
  const int isbf = *flag;
  constexpr int XS = 64 * (K + 8);
  constexpr int OS = CO * 68;
  __shared__ short sh[(XS > OS ? XS : OS)];
  const int b = blockIdx.y, nbase = blockIdx.x * 64, tid = threadIdx.x;
  const int ln = tid & 15, q = (tid >> 4) & 3, wv = tid >> 6;
  constexpr int TPW = CO / 64;
  constexpr int KS = (K == 256) ? 6 : 5;
  for (int it = 0; it < 64 * K / 1024; ++it) {
    int idx4 = it * 256 + tid;
    int n = idx4 >> KS, c4 = (idx4 & ((K / 4) - 1)) * 4;
    *(ushort4*)&sh[n * (K + 8) + c4] =
        *(const ushort4*)(inp + ((size_t)(b * 4096 + nbase + n)) * K + c4);
  }
  __syncthreads();
  f32x4 zero = {0.f, 0.f, 0.f, 0.f};
  f32x4 acc[TPW][4];
  for (int ti = 0; ti < TPW; ++ti) for (int nt = 0; nt < 4; ++nt) acc[ti][nt] = zero;

  for (int kk = 0; kk < K / 32; ++kk) {
    int off = kk * 32 + q * 8;
    bf16x8 bx[4];
    #pragma unroll
    for (int nt = 0; nt < 4; ++nt)
      bx[nt] = *(const bf16x8*)&sh[(16 * nt + ln) * (K + 8) + off];
    #pragma unroll
    for (int ti = 0; ti < TPW; ++ti) {
      bf16x8 aw = load_wfrag(w, isbf, 16 * (TPW * wv + ti) + ln, K, off);
      #pragma unroll
      for (int nt = 0; nt < 4; ++nt)
        acc[ti][nt] = __builtin_amdgcn_mfma_f32_16x16x32_bf16(aw, bx[nt], acc[ti][nt], 0, 0, 0);
    }
  }
  __syncthreads();
  for (int ti = 0; ti < TPW; ++ti)
    for (int r = 0; r < 4; ++r) {
      int co = 16 * (TPW * wv + ti) + q * 4 + r;
      float bb = ldv(bias, isbf, co);
      for (int nt = 0; nt < 4; ++nt)
        sh[co * 68 + 16 * nt + ln] = f2bs(acc[ti][nt][r] + bb);
    }
  __syncthreads();
  for (int it = 0; it < 64 * CO / 1024; ++it) {
    int idx4 = it * 256 + tid;
    int co = idx4 >> 4, n4 = (idx4 & 15) * 4;
    *(ushort4*)(out + ((size_t)(b * CO + co)) * 4096 + nbase + n4) =
        *(const ushort4*)&sh[co * 68 + n4];
  }
}

// ---------------------------------------------------------------------------
// pools — EXACT round-3 versions (validated) + fused variant (validated r8).
// ---------------------------------------------------------------------------
__global__ __launch_bounds__(256) void pool_phi_kernel(
    const short* __restrict__ pc, short* __restrict__ phi)
{
  int idx = blockIdx.x * 256 + threadIdx.x;  // b*1024*128
  int ci = idx & 127, m = (idx >> 7) & 1023, b = idx >> 17;
  int mh = m >> 5, mw = m & 31;
  const short* p = pc + ((size_t)(b * 4096 + (mh * 2) * 64 + mw * 2)) * 128 + ci;
  float v = fmaxf(fmaxf(b2f(p[0]), b2f(p[128])),
                  fmaxf(b2f(p[64 * 128]), b2f(p[65 * 128])));
  phi[idx] = f2bs(v);
}

__global__ __launch_bounds__(256) void pool_g_kernel(
    const short* __restrict__ gc, short* __restrict__ g)
{
  int idx = blockIdx.x * 256 + threadIdx.x;  // (b*128+ci)*1024 + m
  int m = idx & 1023, bc = idx >> 10;
  int mh = m >> 5, mw = m & 31;
  const short* p = gc + (size_t)bc * 4096 + mh * 128 + mw * 2;
  float v = fmaxf(fmaxf(b2f(p[0]), b2f(p[1])), fmaxf(b2f(p[64]), b2f(p[65])));
  g[idx] = f2bs(v);
}

__global__ __launch_bounds__(256) void pool_both_kernel(
    const short* __restrict__ pc, short* __restrict__ phi,
    const short* __restrict__ gc, short* __restrict__ g)
{
  int gidx = blockIdx.x * 256 + threadIdx.x;
  if (gidx < 1048576) {
    int idx = gidx;
    int ci = idx & 127, m = (idx >> 7) & 1023, b = idx >> 17;
    int mh = m >> 5, mw = m & 31;
    const short* p = pc + ((size_t)(b * 4096 + (mh * 2) * 64 + mw * 2)) * 128 + ci;
    float v = fmaxf(fmaxf(b2f(p[0]), b2f(p[128])),
                    fmaxf(b2f(p[64 * 128]), b2f(p[65 * 128])));
    phi[idx] = f2bs(v);
  } else {
    int idx = gidx - 1048576;
    int m = idx & 1023, bc = idx >> 10;
    int mh = m >> 5, mw = m & 31;
    const short* p = gc + (size_t)bc * 4096 + mh * 128 + mw * 2;
    float v = fmaxf(fmaxf(b2f(p[0]), b2f(p[1])), fmaxf(b2f(p[64]), b2f(p[65])));
    g[idx] = f2bs(v);
  }
}

// ---------------------------------------------------------------------------
// attn + convW FUSED — ROUND-17 (= round-16 with the Wy destination FIXED).
// Round-16's NaN: Wy (16.78 MB) was routed into scratch (8.39 MB region) and
// overflowed into phi/gg while blocks still read them. Fix: Wy goes to the
// xT region [0, 16.78M) — exactly 16.78 MB, dead after the conv kernels
// (this is where the validated pipeline put ybuf). attn part = EXACT
// round-6/8 validated body; convW part = EXACT round-4 validated body with
// bx read from ph (attn's y tile, identical [n][136] layout) instead of
// re-staging from global. Saves ybuf 16.8 MB write + read + one launch.
// ---------------------------------------------------------------------------
__global__ __launch_bounds__(256) void attn_convW_k(
    const short* __restrict__ theta, const short* __restrict__ phi,
    const short* __restrict__ g,
    const void* __restrict__ w, const void* __restrict__ bias,
    short* __restrict__ Wy, float* __restrict__ stats,
    const int* __restrict__ flag)
{
  __shared__ short ph[64 * 136];
  __shared__ __align__(16) char rest[36864];
  short* gl = (short*)rest;            // [128][72] during mc loop
  short* Pl = (short*)(rest + 18432);  // [64][72]  during mc loop
  short* shW = (short*)rest;           // [256][72] after the loop (union)

  const int isbf = *flag;
  const int b = blockIdx.y, nbase = blockIdx.x * 64, tid = threadIdx.x;
  const int ln = tid & 15, q = (tid >> 4) & 3, wv = tid >> 6;

  // ---- attn part (validated round-6/8) ----
  const int pm  = tid >> 5;
  const int pc4 = (tid & 31) * 4;
  const int gci = tid >> 4;
  const int gm4 = (tid & 15) * 4;
  const short* phb = phi + (size_t)b * 1024 * 128;
  const short* gb  = g   + (size_t)b * 128 * 1024;

  ushort4 pf_p[8], pf_g[8];
  #pragma unroll
  for (int it = 0; it < 8; ++it)
    pf_p[it] = *(const ushort4*)(phb + ((size_t)(pm + 8 * it)) * 128 + pc4);
  #pragma unroll
  for (int it = 0; it < 8; ++it)
    pf_g[it] = *(const ushort4*)(gb + ((size_t)(gci + 16 * it)) * 1024 + gm4);

  bf16x8 a[4];
  #pragma unroll
  for (int kk = 0; kk < 4; ++kk)
    a[kk] = *(const bf16x8*)(theta +
        ((size_t)(b * 4096 + nbase + 16 * wv + ln)) * 128 + kk * 32 + q * 8);

  f32x4 zero = {0.f, 0.f, 0.f, 0.f};
  f32x4 yacc[8], lacc = zero;
  #pragma unroll
  for (int t = 0; t < 8; ++t) yacc[t] = zero;
  bf16x8 ones;
  #pragma unroll
  for (int j = 0; j < 8; ++j) ones[j] = 0x3F80;

  for (int mc = 0; mc < 16; ++mc) {
    #pragma unroll
    for (int it = 0; it < 8; ++it)
      *(ushort4*)&ph[(pm + 8 * it) * 136 + pc4] = pf_p[it];
    #pragma unroll
    for (int it = 0; it < 8; ++it)
      *(ushort4*)&gl[(gci + 16 * it) * 72 + gm4] = pf_g[it];
    __syncthreads();

    if (mc < 15) {
      const int nmc = mc + 1;
      #pragma unroll
      for (int it = 0; it < 8; ++it)
        pf_p[it] = *(const ushort4*)(phb +
            ((size_t)(nmc * 64 + pm + 8 * it)) * 128 + pc4);
      #pragma unroll
      for (int it = 0; it < 8; ++it)
        pf_g[it] = *(const ushort4*)(gb +
            ((size_t)(gci + 16 * it)) * 1024 + nmc * 64 + gm4);
    }

    #pragma unroll
    for (int t = 0; t < 4; ++t) {
      f32x4 s = zero;
      #pragma unroll
      for (int kk = 0; kk < 4; ++kk) {
        bf16x8 bp = *(const bf16x8*)&ph[(16 * t + ln) * 136 + kk * 32 + q * 8];
        s = __builtin_amdgcn_mfma_f32_16x16x32_bf16(a[kk], bp, s, 0, 0, 0);
      }
      #pragma unroll
      for (int r = 0; r < 4; ++r)
        Pl[(16 * wv + q * 4 + r) * 72 + 16 * t + ln] =
            f2bs(__expf(fminf(s[r], 80.f)));
    }
    bf16x8 ap[2];
    #pragma unroll
    for (int kk = 0; kk < 2; ++kk)
      ap[kk] = *(const bf16x8*)&Pl[(16 * wv + ln) * 72 + kk * 32 + q * 8];
    #pragma unroll
    for (int kk = 0; kk < 2; ++kk)
      lacc = __builtin_amdgcn_mfma_f32_16x16x32_bf16(ap[kk], ones, lacc, 0, 0, 0);
    #pragma unroll
    for (int t = 0; t < 8; ++t) {
      #pragma unroll
      for (int kk = 0; kk < 2; ++kk) {
        bf16x8 bg = *(const bf16x8*)&gl[(16 * t + ln) * 72 + kk * 32 + q * 8];
        yacc[t] = __builtin_amdgcn_mfma_f32_16x16x32_bf16(ap[kk], bg, yacc[t], 0, 0, 0);
      }
    }
    __syncthreads();
  }

  // normalize y into ph (validated epilogue, minus the global write)
  float li[4];
  #pragma unroll
  for (int r = 0; r < 4; ++r) li[r] = 1.0f / lacc[r];
  for (int t = 0; t < 8; ++t)
    for (int r = 0; r < 4; ++r)
      ph[(16 * wv + q * 4 + r) * 136 + 16 * t + ln] = f2bs(yacc[t][r] * li[r]);
  __syncthreads();

  // ---- convW part (validated round-4 body; bx from ph instead of global) --
  f32x4 acc[4][4];
  for (int ti = 0; ti < 4; ++ti)
    for (int nt = 0; nt < 4; ++nt) acc[ti][nt] = zero;

  for (int kk = 0; kk < 4; ++kk) {
    int off = kk * 32 + q * 8;
    bf16x8 bx[4];
    #pragma unroll
    for (int nt = 0; nt < 4; ++nt)
      bx[nt] = *(const bf16x8*)&ph[(16 * nt + ln) * 136 + off];
    #pragma unroll
    for (int ti = 0; ti < 4; ++ti) {
      bf16x8 aw = load_wfrag(w, isbf, 16 * (4 * wv + ti) + ln, 128, off);
      #pragma unroll
      for (int nt = 0; nt < 4; ++nt)
        acc[ti][nt] = __builtin_amdgcn_mfma_f32_16x16x32_bf16(aw, bx[nt], acc[ti][nt], 0, 0, 0);
    }
  }
  // repack into shW (unions dead gl/Pl; ph reads above are done after the
  // MFMA loop's last bx read, and shW writes only touch rest[], not ph)
  #pragma unroll
  for (int ti = 0; ti < 4; ++ti)
    #pragma unroll
    for (int r = 0; r < 4; ++r) {
      int co = 16 * (4 * wv + ti) + 4 * q + r;
      float bb = ldv(bias, isbf, co);
      #pragma unroll
      for (int nt = 0; nt < 4; ++nt)
        shW[co * 72 + 16 * nt + ln] = f2bs(acc[ti][nt][r] + bb);
    }
  __syncthreads();
  {
    int co = tid;
    float s = 0.f, s2 = 0.f;
    for (int i = 0; i < 64; ++i) {
      float v = b2f((unsigned short)shW[co * 72 + i]);
      s += v; s2 += v * v;
    }
    atomicAdd(&stats[co], s);
    atomicAdd(&stats[256 + co], s2);
  }
  for (int it = 0; it < 8; ++it) {
    int idx8 = it * 256 + tid;
    int co = idx8 >> 3, n8 = (idx8 & 7) * 8;
    *(uint4*)(Wy + ((size_t)(b * 256 + co)) * 4096 + nbase + n8) =
        *(const uint4*)&shW[co * 72 + n8];
  }
}

// ---------------------------------------------------------------------------
// BN apply + residual, x4 — EXACT round-4/6 version (validated).
// ---------------------------------------------------------------------------
__global__ __launch_bounds__(256) void bn_apply4(
    const short* __restrict__ Wy, const void* __restrict__ x,
    const float* __restrict__ stats, const void* __restrict__ gamma,
    const void* __restrict__ beta, void* __restrict__ out,
    const int* __restrict__ flag)
{
  const int isbf = *flag;
  int t = blockIdx.x * 256 + threadIdx.x;
  int idx4 = t * 4;
  int c = (idx4 >> 12) & 255;
  float s = stats[c], s2 = stats[256 + c];
  float mean = s * (1.0f / 32768.0f);
  float var = fmaxf(s2 * (1.0f / 32768.0f) - mean * mean, 0.f);
  float scale = rsqrtf(var + 1e-5f) * ldv(gamma, isbf, c);
  float shift = ldv(beta, isbf, c) - mean * scale;
  ushort4 wy = *(const ushort4*)(Wy + idx4);
  float xv[4];
  if (isbf) {
    ushort4 xu = *(const ushort4*)((const unsigned short*)x + idx4);
    xv[0] = b2f(xu.x); xv[1] = b2f(xu.y); xv[2] = b2f(xu.z); xv[3] = b2f(xu.w);
  } else {
    float4 xf = *(const float4*)((const float*)x + idx4);
    xv[0] = xf.x; xv[1] = xf.y; xv[2] = xf.z; xv[3] = xf.w;
  }
  float v0 = b2f(wy.x) * scale + shift + xv[0];
  float v1 = b2f(wy.y) * scale + shift + xv[1];
  float v2 = b2f(wy.z) * scale + shift + xv[2];
  float v3 = b2f(wy.w) * scale + shift + xv[3];
  if (isbf) {
    uint2 o; o.x = pk2(v0, v1); o.y = pk2(v2, v3);
    *(uint2*)((unsigned short*)out + idx4) = o;
  } else {
    float4 o = make_float4(v0, v1, v2, v3);
    *(float4*)((float*)out + idx4) = o;
  }
}

// ---------------------------------------------------------------------------
extern "C" void kernel_launch(void* const* d_in, const int* in_sizes, int n_in,
                              void* d_out, int out_size, void* d_ws, size_t ws_size,
                              hipStream_t stream) {
  const void* x       = d_in[0];
  const void* theta_w = d_in[1];
  const void* theta_b = d_in[2];
  const void* phi_w   = d_in[3];
  const void* phi_b   = d_in[4];
  const void* g_w     = d_in[5];
  const void* g_b     = d_in[6];
  const void* W_w     = d_in[7];
  const void* W_b     = d_in[8];
  const void* gamma   = d_in[9];
  const void* beta    = d_in[10];

  char* wsb = (char*)d_ws;
  // layout:
  //   [0, 16.78M)      xT  -> Wy (xT dead after conv kernels; 16.78M exact)
  //   [16.78M, 25.17M) theta
  //   [25.17M, 33.55M) scratch (phi_c; also g_c on fallback path)
  //   [33.55M, 35.65M) phi   [b][m][ci]
  //   [35.65M, 37.75M) gg    [b][ci][m]
  //   [37.75M, +2048)  stats (512 f32), flag
  //   [37.753M, 46.14M) g_c (fused-conv path only, if ws_size permits)
  short* xT      = (short*)(wsb + 0);
  short* Wy      = (short*)(wsb + 0);
  short* theta   = (short*)(wsb + 16777216);
  short* scratch = (short*)(wsb + 25165824);
  short* phi     = (short*)(wsb + 33554432);
  short* gg      = (short*)(wsb + 35651584);
  float* stats   = (float*)(wsb + 37748736);
  int*   flag    = (int*)  (wsb + 37750784);
  short* g_c     = (short*)(wsb + 37752832);
  const bool fused = ws_size >= (size_t)37752832 + 8388608;

  dim3 blk(256);
  dim3 cgrid(64, 8);
  dim3 tgrid(64, 4, 8);

  hipMemsetAsync(stats, 0, 2048, stream);
  sniff_kernel<<<1, blk, 0, stream>>>((const unsigned short*)x, flag);
  transpose_x<<<tgrid, blk, 0, stream>>>(x, xT, flag);
  if (fused) {
    conv_tpg_k<<<cgrid, blk, 0, stream>>>(xT, theta_w, theta_b, theta,
                                          phi_w, phi_b, scratch,
                                          g_w, g_b, g_c, flag);
    pool_both_kernel<<<8192, blk, 0, stream>>>(scratch, phi, g_c, gg);
  } else {
    conv_tp_k<<<cgrid, blk, 0, stream>>>(xT, theta_w, theta_b, theta,
                                         phi_w, phi_b, scratch, flag);
    pool_phi_kernel<<<4096, blk, 0, stream>>>(scratch, phi);
    conv_n_k<128, 256><<<cgrid, blk, 0, stream>>>(xT, g_w, g_b, scratch, flag);
    pool_g_kernel<<<4096, blk, 0, stream>>>(scratch, gg);
  }
  // attn_convW reads theta/phi/gg, writes Wy -> [0,16.78M): no overlap.
  attn_convW_k<<<cgrid, blk, 0, stream>>>(theta, phi, gg,
                                          W_w, W_b, Wy, stats, flag);
  bn_apply4<<<8192, blk, 0, stream>>>(Wy, x, stats, gamma, beta, d_out, flag);
}

// Round 12
// 217.593 us; speedup vs baseline: 1.2014x; 1.0174x over previous
//
#include <hip/hip_runtime.h>
#include <hip/hip_bf16.h>
#include <cstdint>
#include <math.h>

using bf16 = __hip_bfloat16;
typedef __attribute__((ext_vector_type(8))) short bf16x8;
typedef __attribute__((ext_vector_type(4))) float f32x4;

#define DEV __device__ __forceinline__

DEV float b2f(unsigned short u) { return __uint_as_float(((uint32_t)u) << 16); }
DEV float bfl(bf16 h) { return __bfloat162float(h); }
DEV short f2bs(float f) { bf16 h = __float2bfloat16(f); return *(short*)&h; }
// explicit bf16-pair pack: a in low 16 bits (lower address), b in high.
DEV uint32_t pk2(float a, float b) {
  return (uint32_t)(unsigned short)f2bs(a) |
         ((uint32_t)(unsigned short)f2bs(b) << 16);
}
DEV float ldv(const void* p, int isbf, int i) {
  return isbf ? bfl(((const bf16*)p)[i]) : ((const float*)p)[i];
}

// weight fragment: 8 contiguous elems at w[row*K + off] -> bf16x8
DEV bf16x8 load_wfrag(const void* w, int isbf, int row, int K, int off) {
  bf16x8 r;
  if (isbf) {
    r = *(const bf16x8*)((const short*)w + (size_t)row * K + off);
  } else {
    const float* f = (const float*)w + (size_t)row * K + off;
    float4 a = *(const float4*)f, b = *(const float4*)(f + 4);
    r[0] = f2bs(a.x); r[1] = f2bs(a.y); r[2] = f2bs(a.z); r[3] = f2bs(a.w);
    r[4] = f2bs(b.x); r[5] = f2bs(b.y); r[6] = f2bs(b.z); r[7] = f2bs(b.w);
  }
  return r;
}

// ---------------------------------------------------------------------------
// dtype sniffer — EXACT round-3 version (validated).
// ---------------------------------------------------------------------------
__global__ __launch_bounds__(256) void sniff_kernel(
    const unsigned short* __restrict__ xr, int* __restrict__ flag)
{
  int tid = threadIdx.x;
  int good = 0;
  for (int k = tid; k < 16384; k += 256) {
    unsigned short u = xr[2 * k];
    int e = (u >> 7) & 0xFF;
    good += (e >= 0x6A && e <= 0x86) ? 1 : 0;
  }
  __shared__ int r[256];
  r[tid] = good;
  __syncthreads();
  for (int off = 128; off; off >>= 1) {
    if (tid < off) r[tid] += r[tid + off];
    __syncthreads();
  }
  if (tid == 0) *flag = (r[0] > 9830) ? 1 : 0;
}

// ---------------------------------------------------------------------------
// transpose x [b][c(256)][n(4096)] (flag dtype) -> xT [b][n][c] bf16.
// EXACT round-3 version (validated) — FALLBACK path only.
// ---------------------------------------------------------------------------
__global__ __launch_bounds__(256) void transpose_x(
    const void* __restrict__ x, short* __restrict__ xT, const int* __restrict__ flag)
{
  const int isbf = *flag;
  __shared__ short lt[64 * 71];
  const int n0 = blockIdx.x * 64, c0 = blockIdx.y * 64, b = blockIdx.z;
  const int tid = threadIdx.x;
  for (int it = 0; it < 4; ++it) {
    int idx4 = it * 256 + tid;
    int ci = idx4 >> 4, n4 = (idx4 & 15) * 4;
    size_t go = ((size_t)(b * 256 + c0 + ci)) * 4096 + n0 + n4;
    if (isbf) {
      ushort4 v = *(const ushort4*)((const unsigned short*)x + go);
      lt[ci * 71 + n4 + 0] = v.x; lt[ci * 71 + n4 + 1] = v.y;
      lt[ci * 71 + n4 + 2] = v.z; lt[ci * 71 + n4 + 3] = v.w;
    } else {
      float4 v = *(const float4*)((const float*)x + go);
      lt[ci * 71 + n4 + 0] = f2bs(v.x); lt[ci * 71 + n4 + 1] = f2bs(v.y);
      lt[ci * 71 + n4 + 2] = f2bs(v.z); lt[ci * 71 + n4 + 3] = f2bs(v.w);
    }
  }
  __syncthreads();
  for (int it = 0; it < 4; ++it) {
    int idx4 = it * 256 + tid;
    int n = idx4 >> 4, c4 = (idx4 & 15) * 4;
    ushort4 v;
    v.x = (unsigned short)lt[(c4 + 0) * 71 + n];
    v.y = (unsigned short)lt[(c4 + 1) * 71 + n];
    v.z = (unsigned short)lt[(c4 + 2) * 71 + n];
    v.w = (unsigned short)lt[(c4 + 3) * 71 + n];
    *(ushort4*)(xT + ((size_t)(b * 4096 + n0 + n)) * 256 + c0 + c4) = v;
  }
}

// ---------------------------------------------------------------------------
// conv_tp: FUSED theta+phi 1x1 convs — round-12 version (VALIDATED round 6).
// FALLBACK path only.
// ---------------------------------------------------------------------------
__global__ __launch_bounds__(256) void conv_tp_k(
    const short* __restrict__ xT,
    const void* __restrict__ w1, const void* __restrict__ b1, short* __restrict__ out1,
    const void* __restrict__ w2, const void* __restrict__ b2, short* __restrict__ out2,
    const int* __restrict__ flag)
{
  const int isbf = *flag;
  __shared__ short shA[64 * 264];
  __shared__ short shB[64 * 136];
  const int b = blockIdx.y, nbase = blockIdx.x * 64, tid = threadIdx.x;
  const int ln = tid & 15, q = (tid >> 4) & 3, wv = tid >> 6;
  for (int it = 0; it < 16; ++it) {
    int idx4 = it * 256 + tid;
    int n = idx4 >> 6, c4 = (idx4 & 63) * 4;
    *(ushort4*)&shA[n * 264 + c4] =
        *(const ushort4*)(xT + ((size_t)(b * 4096 + nbase + n)) * 256 + c4);
  }
  __syncthreads();
  f32x4 zero = {0.f, 0.f, 0.f, 0.f};
  f32x4 acc1[4][2], acc2[4][2];
  for (int nt = 0; nt < 4; ++nt)
    for (int ti = 0; ti < 2; ++ti) { acc1[nt][ti] = zero; acc2[nt][ti] = zero; }

  for (int kk = 0; kk < 8; ++kk) {
    int off = kk * 32 + q * 8;
    bf16x8 a[4];
    #pragma unroll
    for (int nt = 0; nt < 4; ++nt)
      a[nt] = *(const bf16x8*)&shA[(16 * nt + ln) * 264 + off];
    #pragma unroll
    for (int ti = 0; ti < 2; ++ti) {
      bf16x8 bw1 = load_wfrag(w1, isbf, 16 * (2 * wv + ti) + ln, 256, off);
      #pragma unroll
      for (int nt = 0; nt < 4; ++nt)
        acc1[nt][ti] = __builtin_amdgcn_mfma_f32_16x16x32_bf16(a[nt], bw1, acc1[nt][ti], 0, 0, 0);
    }
    #pragma unroll
    for (int ti = 0; ti < 2; ++ti) {
      bf16x8 bw2 = load_wfrag(w2, isbf, 16 * (2 * wv + ti) + ln, 256, off);
      #pragma unroll
      for (int nt = 0; nt < 4; ++nt)
        acc2[nt][ti] = __builtin_amdgcn_mfma_f32_16x16x32_bf16(a[nt], bw2, acc2[nt][ti], 0, 0, 0);
    }
  }
  {
    float bv[2];
    for (int ti = 0; ti < 2; ++ti) bv[ti] = ldv(b1, isbf, 16 * (2 * wv + ti) + ln);
    for (int nt = 0; nt < 4; ++nt)
      for (int ti = 0; ti < 2; ++ti)
        for (int r = 0; r < 4; ++r)
          shB[(16 * nt + q * 4 + r) * 136 + 16 * (2 * wv + ti) + ln] =
              f2bs(acc1[nt][ti][r] + bv[ti]);
    __syncthreads();
    for (int it = 0; it < 8; ++it) {
      int idx4 = it * 256 + tid;
      int n = idx4 >> 5, c4 = (idx4 & 31) * 4;
      *(ushort4*)(out1 + ((size_t)(b * 4096 + nbase + n)) * 128 + c4) =
          *(const ushort4*)&shB[n * 136 + c4];
    }
    __syncthreads();
  }
  {
    float bv[2];
    for (int ti = 0; ti < 2; ++ti) bv[ti] = ldv(b2, isbf, 16 * (2 * wv + ti) + ln);
    for (int nt = 0; nt < 4; ++nt)
      for (int ti = 0; ti < 2; ++ti)
        for (int r = 0; r < 4; ++r)
          shB[(16 * nt + q * 4 + r) * 136 + 16 * (2 * wv + ti) + ln] =
              f2bs(acc2[nt][ti][r] + bv[ti]);
    __syncthreads();
    for (int it = 0; it < 8; ++it) {
      int idx4 = it * 256 + tid;
      int n = idx4 >> 5, c4 = (idx4 & 31) * 4;
      *(ushort4*)(out2 + ((size_t)(b * 4096 + nbase + n)) * 128 + c4) =
          *(const ushort4*)&shB[n * 136 + c4];
    }
  }
}

// ---------------------------------------------------------------------------
// conv_xtpg: transpose + FUSED theta+phi+g 1x1 convs — ROUND-18 (under test).
// Staging now reads x [b][c][n] DIRECTLY (coalesced along n, exactly
// transpose_x's validated load side) and scatter-writes the transposed
// scalars into shA[n][264]. Eliminates the entire transpose_x kernel and
// xT's 16.8 MB write + 16.8 MB read. Everything below the staging barrier
// is byte-identical to the VALIDATED round-8 conv_tpg.
// ---------------------------------------------------------------------------
__global__ __launch_bounds__(256) void conv_xtpg_k(
    const void* __restrict__ x,
    const void* __restrict__ w1, const void* __restrict__ b1, short* __restrict__ out1,
    const void* __restrict__ w2, const void* __restrict__ b2, short* __restrict__ out2,
    const void* __restrict__ w3, const void* __restrict__ b3, short* __restrict__ out3,
    const int* __restrict__ flag)
{
  const int isbf = *flag;
  __shared__ short shA[64 * 264];   // x tile, transposed to [n][c] layout
  __shared__ short shB[8704];       // repack region (64*136 == 128*68)
  const int b = blockIdx.y, nbase = blockIdx.x * 64, tid = threadIdx.x;
  const int ln = tid & 15, q = (tid >> 4) & 3, wv = tid >> 6;
  // transpose-staging: thread handles channel ch, n-span n4..n4+3
  for (int it = 0; it < 16; ++it) {
    int idx4 = it * 256 + tid;
    int ch = idx4 >> 4, n4 = (idx4 & 15) * 4;
    size_t go = ((size_t)(b * 256 + ch)) * 4096 + nbase + n4;
    if (isbf) {
      ushort4 v = *(const ushort4*)((const unsigned short*)x + go);
      shA[(n4 + 0) * 264 + ch] = v.x; shA[(n4 + 1) * 264 + ch] = v.y;
      shA[(n4 + 2) * 264 + ch] = v.z; shA[(n4 + 3) * 264 + ch] = v.w;
    } else {
      float4 v = *(const float4*)((const float*)x + go);
      shA[(n4 + 0) * 264 + ch] = f2bs(v.x); shA[(n4 + 1) * 264 + ch] = f2bs(v.y);
      shA[(n4 + 2) * 264 + ch] = f2bs(v.z); shA[(n4 + 3) * 264 + ch] = f2bs(v.w);
    }
  }
  __syncthreads();
  f32x4 zero = {0.f, 0.f, 0.f, 0.f};
  f32x4 acc1[4][2], acc2[4][2], acc3[2][4];
  for (int nt = 0; nt < 4; ++nt)
    for (int ti = 0; ti < 2; ++ti) { acc1[nt][ti] = zero; acc2[nt][ti] = zero; }
  for (int ti = 0; ti < 2; ++ti)
    for (int nt = 0; nt < 4; ++nt) acc3[ti][nt] = zero;

  for (int kk = 0; kk < 8; ++kk) {
    int off = kk * 32 + q * 8;
    bf16x8 a[4];
    #pragma unroll
    for (int nt = 0; nt < 4; ++nt)
      a[nt] = *(const bf16x8*)&shA[(16 * nt + ln) * 264 + off];
    #pragma unroll
    for (int ti = 0; ti < 2; ++ti) {
      bf16x8 bw1 = load_wfrag(w1, isbf, 16 * (2 * wv + ti) + ln, 256, off);
      #pragma unroll
      for (int nt = 0; nt < 4; ++nt)
        acc1[nt][ti] = __builtin_amdgcn_mfma_f32_16x16x32_bf16(a[nt], bw1, acc1[nt][ti], 0, 0, 0);
    }
    #pragma unroll
    for (int ti = 0; ti < 2; ++ti) {
      bf16x8 bw2 = load_wfrag(w2, isbf, 16 * (2 * wv + ti) + ln, 256, off);
      #pragma unroll
      for (int nt = 0; nt < 4; ++nt)
        acc2[nt][ti] = __builtin_amdgcn_mfma_f32_16x16x32_bf16(a[nt], bw2, acc2[nt][ti], 0, 0, 0);
    }
    #pragma unroll
    for (int ti = 0; ti < 2; ++ti) {
      bf16x8 aw3 = load_wfrag(w3, isbf, 16 * (2 * wv + ti) + ln, 256, off);
      #pragma unroll
      for (int nt = 0; nt < 4; ++nt)
        acc3[ti][nt] = __builtin_amdgcn_mfma_f32_16x16x32_bf16(aw3, a[nt], acc3[ti][nt], 0, 0, 0);
    }
  }
  // epilogue 1 (theta -> out1 [b][n][128])
  {
    float bv[2];
    for (int ti = 0; ti < 2; ++ti) bv[ti] = ldv(b1, isbf, 16 * (2 * wv + ti) + ln);
    for (int nt = 0; nt < 4; ++nt)
      for (int ti = 0; ti < 2; ++ti)
        for (int r = 0; r < 4; ++r)
          shB[(16 * nt + q * 4 + r) * 136 + 16 * (2 * wv + ti) + ln] =
              f2bs(acc1[nt][ti][r] + bv[ti]);
    __syncthreads();
    for (int it = 0; it < 8; ++it) {
      int idx4 = it * 256 + tid;
      int n = idx4 >> 5, c4 = (idx4 & 31) * 4;
      *(ushort4*)(out1 + ((size_t)(b * 4096 + nbase + n)) * 128 + c4) =
          *(const ushort4*)&shB[n * 136 + c4];
    }
    __syncthreads();
  }
  // epilogue 2 (phi_c -> out2 [b][n][128])
  {
    float bv[2];
    for (int ti = 0; ti < 2; ++ti) bv[ti] = ldv(b2, isbf, 16 * (2 * wv + ti) + ln);
    for (int nt = 0; nt < 4; ++nt)
      for (int ti = 0; ti < 2; ++ti)
        for (int r = 0; r < 4; ++r)
          shB[(16 * nt + q * 4 + r) * 136 + 16 * (2 * wv + ti) + ln] =
              f2bs(acc2[nt][ti][r] + bv[ti]);
    __syncthreads();
    for (int it = 0; it < 8; ++it) {
      int idx4 = it * 256 + tid;
      int n = idx4 >> 5, c4 = (idx4 & 31) * 4;
      *(ushort4*)(out2 + ((size_t)(b * 4096 + nbase + n)) * 128 + c4) =
          *(const ushort4*)&shB[n * 136 + c4];
    }
    __syncthreads();
  }
  // epilogue 3 (g_c -> out3 [b][128][n], validated conv_n CO=128 pattern)
  {
    for (int ti = 0; ti < 2; ++ti)
      for (int r = 0; r < 4; ++r) {
        int co = 16 * (2 * wv + ti) + q * 4 + r;
        float bb = ldv(b3, isbf, co);
        for (int nt = 0; nt < 4; ++nt)
          shB[co * 68 + 16 * nt + ln] = f2bs(acc3[ti][nt][r] + bb);
      }
    __syncthreads();
    for (int it = 0; it < 8; ++it) {
      int idx4 = it * 256 + tid;
      int co = idx4 >> 4, n4 = (idx4 & 15) * 4;
      *(ushort4*)(out3 + ((size_t)(b * 128 + co)) * 4096 + nbase + n4) =
          *(const ushort4*)&shB[co * 68 + n4];
    }
  }
}

// ---------------------------------------------------------------------------
// conv_n: out[b][CO][n] — EXACT round-3 version (validated, fallback path).
// ---------------------------------------------------------------------------
template<int CO, int K>
__global__ __launch_bounds__(256) void conv_n_k(
    const short* __restrict__ inp, const void* __restrict__ w,
    const void* __restrict__ bias, short* __restrict__ out,
    const int* __restrict__ flag)
{
  const int isbf = *flag;
  constexpr int XS = 64 * (K + 8);
  constexpr int OS = CO * 68;
  __shared__ short sh[(XS > OS ? XS : OS)];
  const int b = blockIdx.y, nbase = blockIdx.x * 64, tid = threadIdx.x;
  const int ln = tid & 15, q = (tid >> 4) & 3, wv = tid >> 6;
  constexpr int TPW = CO / 64;
  constexpr int KS = (K == 256) ? 6 : 5;
  for (int it = 0; it < 64 * K / 1024; ++it) {
    int idx4 = it * 256 + tid;
    int n = idx4 >> KS, c4 = (idx4 & ((K / 4) - 1)) * 4;
    *(ushort4*)&sh[n * (K + 8) + c4] =
        *(const ushort4*)(inp + ((size_t)(b * 4096 + nbase + n)) * K + c4);
  }
  __syncthreads();
  f32x4 zero = {0.f, 0.f, 0.f, 0.f};
  f32x4 acc[TPW][4];
  for (int ti = 0; ti < TPW; ++ti) for (int nt = 0; nt < 4; ++nt) acc[ti][nt] = zero;

  for (int kk = 0; kk < K / 32; ++kk) {
    int off = kk * 32 + q * 8;
    bf16x8 bx[4];
    #pragma unroll
    for (int nt = 0; nt < 4; ++nt)
      bx[nt] = *(const bf16x8*)&sh[(16 * nt + ln) * (K + 8) + off];
    #pragma unroll
    for (int ti = 0; ti < TPW; ++ti) {
      bf16x8 aw = load_wfrag(w, isbf, 16 * (TPW * wv + ti) + ln, K, off);
      #pragma unroll
      for (int nt = 0; nt < 4; ++nt)
        acc[ti][nt] = __builtin_amdgcn_mfma_f32_16x16x32_bf16(aw, bx[nt], acc[ti][nt], 0, 0, 0);
    }
  }
  __syncthreads();
  for (int ti = 0; ti < TPW; ++ti)
    for (int r = 0; r < 4; ++r) {
      int co = 16 * (TPW * wv + ti) + q * 4 + r;
      float bb = ldv(bias, isbf, co);
      for (int nt = 0; nt < 4; ++nt)
        sh[co * 68 + 16 * nt + ln] = f2bs(acc[ti][nt][r] + bb);
    }
  __syncthreads();
  for (int it = 0; it < 64 * CO / 1024; ++it) {
    int idx4 = it * 256 + tid;
    int co = idx4 >> 4, n4 = (idx4 & 15) * 4;
    *(ushort4*)(out + ((size_t)(b * CO + co)) * 4096 + nbase + n4) =
        *(const ushort4*)&sh[co * 68 + n4];
  }
}

// ---------------------------------------------------------------------------
// pools — EXACT round-3 versions (validated) + fused variant (validated r8).
// ---------------------------------------------------------------------------
__global__ __launch_bounds__(256) void pool_phi_kernel(
    const short* __restrict__ pc, short* __restrict__ phi)
{
  int idx = blockIdx.x * 256 + threadIdx.x;  // b*1024*128
  int ci = idx & 127, m = (idx >> 7) & 1023, b = idx >> 17;
  int mh = m >> 5, mw = m & 31;
  const short* p = pc + ((size_t)(b * 4096 + (mh * 2) * 64 + mw * 2)) * 128 + ci;
  float v = fmaxf(fmaxf(b2f(p[0]), b2f(p[128])),
                  fmaxf(b2f(p[64 * 128]), b2f(p[65 * 128])));
  phi[idx] = f2bs(v);
}

__global__ __launch_bounds__(256) void pool_g_kernel(
    const short* __restrict__ gc, short* __restrict__ g)
{
  int idx = blockIdx.x * 256 + threadIdx.x;  // (b*128+ci)*1024 + m
  int m = idx & 1023, bc = idx >> 10;
  int mh = m >> 5, mw = m & 31;
  const short* p = gc + (size_t)bc * 4096 + mh * 128 + mw * 2;
  float v = fmaxf(fmaxf(b2f(p[0]), b2f(p[1])), fmaxf(b2f(p[64]), b2f(p[65])));
  g[idx] = f2bs(v);
}

__global__ __launch_bounds__(256) void pool_both_kernel(
    const short* __restrict__ pc, short* __restrict__ phi,
    const short* __restrict__ gc, short* __restrict__ g)
{
  int gidx = blockIdx.x * 256 + threadIdx.x;
  if (gidx < 1048576) {
    int idx = gidx;
    int ci = idx & 127, m = (idx >> 7) & 1023, b = idx >> 17;
    int mh = m >> 5, mw = m & 31;
    const short* p = pc + ((size_t)(b * 4096 + (mh * 2) * 64 + mw * 2)) * 128 + ci;
    float v = fmaxf(fmaxf(b2f(p[0]), b2f(p[128])),
                    fmaxf(b2f(p[64 * 128]), b2f(p[65 * 128])));
    phi[idx] = f2bs(v);
  } else {
    int idx = gidx - 1048576;
    int m = idx & 1023, bc = idx >> 10;
    int mh = m >> 5, mw = m & 31;
    const short* p = gc + (size_t)bc * 4096 + mh * 128 + mw * 2;
    float v = fmaxf(fmaxf(b2f(p[0]), b2f(p[1])), fmaxf(b2f(p[64]), b2f(p[65])));
    g[idx] = f2bs(v);
  }
}

// ---------------------------------------------------------------------------
// attn + convW FUSED — VALIDATED round 11 (67.9 us).
// ---------------------------------------------------------------------------
__global__ __launch_bounds__(256) void attn_convW_k(
    const short* __restrict__ theta, const short* __restrict__ phi,
    const short* __restrict__ g,
    const void* __restrict__ w, const void* __restrict__ bias,
    short* __restrict__ Wy, float* __restrict__ stats,
    const int* __restrict__ flag)
{
  __shared__ short ph[64 * 136];
  __shared__ __align__(16) char rest[36864];
  short* gl = (short*)rest;            // [128][72] during mc loop
  short* Pl = (short*)(rest + 18432);  // [64][72]  during mc loop
  short* shW = (short*)rest;           // [256][72] after the loop (union)

  const int isbf = *flag;
  const int b = blockIdx.y, nbase = blockIdx.x * 64, tid = threadIdx.x;
  const int ln = tid & 15, q = (tid >> 4) & 3, wv = tid >> 6;

  // ---- attn part (validated round-6/8) ----
  const int pm  = tid >> 5;
  const int pc4 = (tid & 31) * 4;
  const int gci = tid >> 4;
  const int gm4 = (tid & 15) * 4;
  const short* phb = phi + (size_t)b * 1024 * 128;
  const short* gb  = g   + (size_t)b * 128 * 1024;

  ushort4 pf_p[8], pf_g[8];
  #pragma unroll
  for (int it = 0; it < 8; ++it)
    pf_p[it] = *(const ushort4*)(phb + ((size_t)(pm + 8 * it)) * 128 + pc4);
  #pragma unroll
  for (int it = 0; it < 8; ++it)
    pf_g[it] = *(const ushort4*)(gb + ((size_t)(gci + 16 * it)) * 1024 + gm4);

  bf16x8 a[4];
  #pragma unroll
  for (int kk = 0; kk < 4; ++kk)
    a[kk] = *(const bf16x8*)(theta +
        ((size_t)(b * 4096 + nbase + 16 * wv + ln)) * 128 + kk * 32 + q * 8);

  f32x4 zero = {0.f, 0.f, 0.f, 0.f};
  f32x4 yacc[8], lacc = zero;
  #pragma unroll
  for (int t = 0; t < 8; ++t) yacc[t] = zero;
  bf16x8 ones;
  #pragma unroll
  for (int j = 0; j < 8; ++j) ones[j] = 0x3F80;

  for (int mc = 0; mc < 16; ++mc) {
    #pragma unroll
    for (int it = 0; it < 8; ++it)
      *(ushort4*)&ph[(pm + 8 * it) * 136 + pc4] = pf_p[it];
    #pragma unroll
    for (int it = 0; it < 8; ++it)
      *(ushort4*)&gl[(gci + 16 * it) * 72 + gm4] = pf_g[it];
    __syncthreads();

    if (mc < 15) {
      const int nmc = mc + 1;
      #pragma unroll
      for (int it = 0; it < 8; ++it)
        pf_p[it] = *(const ushort4*)(phb +
            ((size_t)(nmc * 64 + pm + 8 * it)) * 128 + pc4);
      #pragma unroll
      for (int it = 0; it < 8; ++it)
        pf_g[it] = *(const ushort4*)(gb +
            ((size_t)(gci + 16 * it)) * 1024 + nmc * 64 + gm4);
    }

    #pragma unroll
    for (int t = 0; t < 4; ++t) {
      f32x4 s = zero;
      #pragma unroll
      for (int kk = 0; kk < 4; ++kk) {
        bf16x8 bp = *(const bf16x8*)&ph[(16 * t + ln) * 136 + kk * 32 + q * 8];
        s = __builtin_amdgcn_mfma_f32_16x16x32_bf16(a[kk], bp, s, 0, 0, 0);
      }
      #pragma unroll
      for (int r = 0; r < 4; ++r)
        Pl[(16 * wv + q * 4 + r) * 72 + 16 * t + ln] =
            f2bs(__expf(fminf(s[r], 80.f)));
    }
    bf16x8 ap[2];
    #pragma unroll
    for (int kk = 0; kk < 2; ++kk)
      ap[kk] = *(const bf16x8*)&Pl[(16 * wv + ln) * 72 + kk * 32 + q * 8];
    #pragma unroll
    for (int kk = 0; kk < 2; ++kk)
      lacc = __builtin_amdgcn_mfma_f32_16x16x32_bf16(ap[kk], ones, lacc, 0, 0, 0);
    #pragma unroll
    for (int t = 0; t < 8; ++t) {
      #pragma unroll
      for (int kk = 0; kk < 2; ++kk) {
        bf16x8 bg = *(const bf16x8*)&gl[(16 * t + ln) * 72 + kk * 32 + q * 8];
        yacc[t] = __builtin_amdgcn_mfma_f32_16x16x32_bf16(ap[kk], bg, yacc[t], 0, 0, 0);
      }
    }
    __syncthreads();
  }

  // normalize y into ph (validated epilogue, minus the global write)
  float li[4];
  #pragma unroll
  for (int r = 0; r < 4; ++r) li[r] = 1.0f / lacc[r];
  for (int t = 0; t < 8; ++t)
    for (int r = 0; r < 4; ++r)
      ph[(16 * wv + q * 4 + r) * 136 + 16 * t + ln] = f2bs(yacc[t][r] * li[r]);
  __syncthreads();

  // ---- convW part (validated round-4 body; bx from ph instead of global) --
  f32x4 acc[4][4];
  for (int ti = 0; ti < 4; ++ti)
    for (int nt = 0; nt < 4; ++nt) acc[ti][nt] = zero;

  for (int kk = 0; kk < 4; ++kk) {
    int off = kk * 32 + q * 8;
    bf16x8 bx[4];
    #pragma unroll
    for (int nt = 0; nt < 4; ++nt)
      bx[nt] = *(const bf16x8*)&ph[(16 * nt + ln) * 136 + off];
    #pragma unroll
    for (int ti = 0; ti < 4; ++ti) {
      bf16x8 aw = load_wfrag(w, isbf, 16 * (4 * wv + ti) + ln, 128, off);
      #pragma unroll
      for (int nt = 0; nt < 4; ++nt)
        acc[ti][nt] = __builtin_amdgcn_mfma_f32_16x16x32_bf16(aw, bx[nt], acc[ti][nt], 0, 0, 0);
    }
  }
  #pragma unroll
  for (int ti = 0; ti < 4; ++ti)
    #pragma unroll
    for (int r = 0; r < 4; ++r) {
      int co = 16 * (4 * wv + ti) + 4 * q + r;
      float bb = ldv(bias, isbf, co);
      #pragma unroll
      for (int nt = 0; nt < 4; ++nt)
        shW[co * 72 + 16 * nt + ln] = f2bs(acc[ti][nt][r] + bb);
    }
  __syncthreads();
  {
    int co = tid;
    float s = 0.f, s2 = 0.f;
    for (int i = 0; i < 64; ++i) {
      float v = b2f((unsigned short)shW[co * 72 + i]);
      s += v; s2 += v * v;
    }
    atomicAdd(&stats[co], s);
    atomicAdd(&stats[256 + co], s2);
  }
  for (int it = 0; it < 8; ++it) {
    int idx8 = it * 256 + tid;
    int co = idx8 >> 3, n8 = (idx8 & 7) * 8;
    *(uint4*)(Wy + ((size_t)(b * 256 + co)) * 4096 + nbase + n8) =
        *(const uint4*)&shW[co * 72 + n8];
  }
}

// ---------------------------------------------------------------------------
// BN apply + residual, x4 — EXACT round-4/6 version (validated).
// ---------------------------------------------------------------------------
__global__ __launch_bounds__(256) void bn_apply4(
    const short* __restrict__ Wy, const void* __restrict__ x,
    const float* __restrict__ stats, const void* __restrict__ gamma,
    const void* __restrict__ beta, void* __restrict__ out,
    const int* __restrict__ flag)
{
  const int isbf = *flag;
  int t = blockIdx.x * 256 + threadIdx.x;
  int idx4 = t * 4;
  int c = (idx4 >> 12) & 255;
  float s = stats[c], s2 = stats[256 + c];
  float mean = s * (1.0f / 32768.0f);
  float var = fmaxf(s2 * (1.0f / 32768.0f) - mean * mean, 0.f);
  float scale = rsqrtf(var + 1e-5f) * ldv(gamma, isbf, c);
  float shift = ldv(beta, isbf, c) - mean * scale;
  ushort4 wy = *(const ushort4*)(Wy + idx4);
  float xv[4];
  if (isbf) {
    ushort4 xu = *(const ushort4*)((const unsigned short*)x + idx4);
    xv[0] = b2f(xu.x); xv[1] = b2f(xu.y); xv[2] = b2f(xu.z); xv[3] = b2f(xu.w);
  } else {
    float4 xf = *(const float4*)((const float*)x + idx4);
    xv[0] = xf.x; xv[1] = xf.y; xv[2] = xf.z; xv[3] = xf.w;
  }
  float v0 = b2f(wy.x) * scale + shift + xv[0];
  float v1 = b2f(wy.y) * scale + shift + xv[1];
  float v2 = b2f(wy.z) * scale + shift + xv[2];
  float v3 = b2f(wy.w) * scale + shift + xv[3];
  if (isbf) {
    uint2 o; o.x = pk2(v0, v1); o.y = pk2(v2, v3);
    *(uint2*)((unsigned short*)out + idx4) = o;
  } else {
    float4 o = make_float4(v0, v1, v2, v3);
    *(float4*)((float*)out + idx4) = o;
  }
}

// ---------------------------------------------------------------------------
extern "C" void kernel_launch(void* const* d_in, const int* in_sizes, int n_in,
                              void* d_out, int out_size, void* d_ws, size_t ws_size,
                              hipStream_t stream) {
  const void* x       = d_in[0];
  const void* theta_w = d_in[1];
  const void* theta_b = d_in[2];
  const void* phi_w   = d_in[3];
  const void* phi_b   = d_in[4];
  const void* g_w     = d_in[5];
  const void* g_b     = d_in[6];
  const void* W_w     = d_in[7];
  const void* W_b     = d_in[8];
  const void* gamma   = d_in[9];
  const void* beta    = d_in[10];

  char* wsb = (char*)d_ws;
  // layout:
  //   [0, 16.78M)      xT (fallback only) -> Wy
  //   [16.78M, 25.17M) theta
  //   [25.17M, 33.55M) scratch (phi_c; also g_c on fallback path)
  //   [33.55M, 35.65M) phi   [b][m][ci]
  //   [35.65M, 37.75M) gg    [b][ci][m]
  //   [37.75M, +2048)  stats (512 f32), flag
  //   [37.753M, 46.14M) g_c (fused-conv path only, if ws_size permits)
  short* xT      = (short*)(wsb + 0);
  short* Wy      = (short*)(wsb + 0);
  short* theta   = (short*)(wsb + 16777216);
  short* scratch = (short*)(wsb + 25165824);
  short* phi     = (short*)(wsb + 33554432);
  short* gg      = (short*)(wsb + 35651584);
  float* stats   = (float*)(wsb + 37748736);
  int*   flag    = (int*)  (wsb + 37750784);
  short* g_c     = (short*)(wsb + 37752832);
  const bool fused = ws_size >= (size_t)37752832 + 8388608;

  dim3 blk(256);
  dim3 cgrid(64, 8);
  dim3 tgrid(64, 4, 8);

  hipMemsetAsync(stats, 0, 2048, stream);
  sniff_kernel<<<1, blk, 0, stream>>>((const unsigned short*)x, flag);
  if (fused) {
    // transpose folded into conv staging; no xT materialization at all.
    conv_xtpg_k<<<cgrid, blk, 0, stream>>>(x, theta_w, theta_b, theta,
                                           phi_w, phi_b, scratch,
                                           g_w, g_b, g_c, flag);
    pool_both_kernel<<<8192, blk, 0, stream>>>(scratch, phi, g_c, gg);
  } else {
    transpose_x<<<tgrid, blk, 0, stream>>>(x, xT, flag);
    conv_tp_k<<<cgrid, blk, 0, stream>>>(xT, theta_w, theta_b, theta,
                                         phi_w, phi_b, scratch, flag);
    pool_phi_kernel<<<4096, blk, 0, stream>>>(scratch, phi);
    conv_n_k<128, 256><<<cgrid, blk, 0, stream>>>(xT, g_w, g_b, scratch, flag);
    pool_g_kernel<<<4096, blk, 0, stream>>>(scratch, gg);
  }
  // attn_convW reads theta/phi/gg, writes Wy -> [0,16.78M): no overlap.
  attn_convW_k<<<cgrid, blk, 0, stream>>>(theta, phi, gg,
                                          W_w, W_b, Wy, stats, flag);
  bn_apply4<<<8192, blk, 0, stream>>>(Wy, x, stats, gamma, beta, d_out, flag);
}